// Round 12
// baseline (1045.090 us; speedup 1.0000x reference)
//
#include <hip/hip_runtime.h>

#define EMB 256
typedef unsigned short u16;
typedef __attribute__((ext_vector_type(8))) short short8v;
typedef __attribute__((ext_vector_type(4))) short short4v;
typedef __attribute__((ext_vector_type(4))) float f32x4;

__device__ inline u16 f2bf(float x){
  union{float f; unsigned u;} c; c.f = x;
  unsigned r = c.u + 0x7FFFu + ((c.u>>16)&1u);
  return (u16)(r>>16);
}
__device__ inline float bf2f(u16 h){
  union{unsigned u; float f;} c; c.u = ((unsigned)h) << 16; return c.f;
}

// ---------------- DDE: counts + round-1 scatter fused ----------------
__global__ void k_scatter1(const int* __restrict__ h_id, const int* __restrict__ t_id,
                           const float* __restrict__ topic,
                           float* __restrict__ cnt_f, float* __restrict__ cnt_r,
                           float* __restrict__ accf, float* __restrict__ accr, int E) {
  int e = blockIdx.x * 256 + threadIdx.x;
  if (e >= E) return;
  int h = h_id[e], t = t_id[e];
  atomicAdd(&cnt_f[t], 1.0f);
  atomicAdd(&cnt_r[h], 1.0f);
  float a0 = topic[2*h+0], a1 = topic[2*h+1];
  if (a0 != 0.f) atomicAdd(&accf[2*t+0], a0);
  if (a1 != 0.f) atomicAdd(&accf[2*t+1], a1);
  float c0 = topic[2*t+0], c1 = topic[2*t+1];
  if (c0 != 0.f) atomicAdd(&accr[2*h+0], c0);
  if (c1 != 0.f) atomicAdd(&accr[2*h+1], c1);
}

// block 0: gate softmax + qpart; blocks 1..gN: div1
__global__ void k_div1_gate(const float* __restrict__ topic,
                            const float* __restrict__ cnt_f, const float* __restrict__ cnt_r,
                            const float* __restrict__ accf, const float* __restrict__ accr,
                            float* __restrict__ pos, int N,
                            const float* __restrict__ q, const float* __restrict__ Wg,
                            const float* __restrict__ bg, const float* __restrict__ W1,
                            const float* __restrict__ b1, float* __restrict__ gateq) {
  int t = threadIdx.x;
  if (blockIdx.x == 0) {
    __shared__ float qs[256];
    __shared__ float z[3];
    qs[t] = q[t];
    __syncthreads();
    if (t < 3) {
      float s = bg[t];
      for (int k = 0; k < 256; ++k) s += qs[k] * Wg[k*3 + t];
      z[t] = s;
    }
    __syncthreads();
    if (t == 0) {
      float m = fmaxf(z[0], fmaxf(z[1], z[2]));
      float e0 = expf(z[0]-m), e1 = expf(z[1]-m), e2 = expf(z[2]-m);
      float s = e0 + e1 + e2;
      gateq[0] = e0/s; gateq[1] = e1/s; gateq[2] = e2/s; gateq[3] = 0.f;
    }
    float a = b1[t];
    for (int k = 0; k < 256; ++k) a += qs[k] * W1[k*256 + t];
    gateq[4 + t] = a;
    return;
  }
  int n = (blockIdx.x - 1) * 256 + t;
  if (n >= N) return;
  float cf = fmaxf(cnt_f[n], 1.0f), cr = fmaxf(cnt_r[n], 1.0f);
  pos[10*n+0] = topic[2*n+0];
  pos[10*n+1] = topic[2*n+1];
  pos[10*n+2] = accf[2*n+0] / cf;
  pos[10*n+3] = accf[2*n+1] / cf;
  pos[10*n+6] = accr[2*n+0] / cr;
  pos[10*n+7] = accr[2*n+1] / cr;
}

__global__ void k_scatter2(const int* __restrict__ h_id, const int* __restrict__ t_id,
                           const float* __restrict__ pos,
                           float* __restrict__ accf, float* __restrict__ accr, int E) {
  int e = blockIdx.x * 256 + threadIdx.x;
  if (e >= E) return;
  int h = h_id[e], t = t_id[e];
  float a0 = pos[10*h+2], a1 = pos[10*h+3];
  if (a0 != 0.f) atomicAdd(&accf[2*t+0], a0);
  if (a1 != 0.f) atomicAdd(&accf[2*t+1], a1);
  float c0 = pos[10*t+6], c1 = pos[10*t+7];
  if (c0 != 0.f) atomicAdd(&accr[2*h+0], c0);
  if (c1 != 0.f) atomicAdd(&accr[2*h+1], c1);
}

__global__ void k_div2(const float* __restrict__ cnt_f, const float* __restrict__ cnt_r,
                       const float* __restrict__ accf, const float* __restrict__ accr,
                       float* __restrict__ pos, int N) {
  int n = blockIdx.x * 256 + threadIdx.x;
  if (n >= N) return;
  float cf = fmaxf(cnt_f[n], 1.0f), cr = fmaxf(cnt_r[n], 1.0f);
  pos[10*n+4] = accf[2*n+0] / cf;
  pos[10*n+5] = accf[2*n+1] / cf;
  pos[10*n+8] = accr[2*n+0] / cr;
  pos[10*n+9] = accr[2*n+1] / cr;
}

// ---------------- weight transforms ----------------
// WB: 8 A-frag chunks of W1[256:512] (layer 1).
// WN: B-frags for k_node nb GEMM (8 chunks x 32 col-tiles), cols = [Wnb_top | Wnb_bot].
// WP: B-frags for k_node pos GEMM (1 chunk x 32 col-tiles), K rows: k<10 = g1*Wpos(h|t),
//     k==10 = g1*b_pos (cols<256 only), else 0.
// MW: [17][256] bf16 = g2 * motif_emb @ W_str[256:320], row 0 = 0 (padding_idx).
__global__ void k_wtrans(const float* __restrict__ Wpos, const float* __restrict__ Wstr,
                         const float* __restrict__ W1, const float* __restrict__ Wnb,
                         const float* __restrict__ bpos, const float* __restrict__ motif,
                         const float* __restrict__ gateq,
                         u16* __restrict__ WB, u16* __restrict__ WN,
                         u16* __restrict__ WP, u16* __restrict__ MW) {
  int gid = blockIdx.x * 256 + threadIdx.x;
  if (gid < 8192) {                       // WB: W1 bottom, frag layout
    int lane = gid & 63, ft = (gid >> 6) & 15, kt = gid >> 10;
    int n  = ft*16 + (lane & 15);
    int k0 = kt*32 + (lane >> 4) * 8;
    short8v v;
    #pragma unroll
    for (int j = 0; j < 8; ++j)
      v[j] = (short)f2bf(W1[(size_t)(256 + k0 + j)*256 + n]);
    *(short8v*)(WB + (size_t)gid * 8) = v;
  } else if (gid < 24576) {               // WN
    int g = gid - 8192;
    int lane = g & 63, nt = (g >> 6) & 31, kc = g >> 11;
    int col = nt*16 + (lane & 15);
    int k0  = kc*32 + (lane >> 4) * 8;
    short8v v;
    #pragma unroll
    for (int j = 0; j < 8; ++j) {
      int k = k0 + j;
      float x = (col < 256) ? Wnb[(size_t)k*256 + col] : Wnb[(size_t)(256+k)*256 + (col-256)];
      v[j] = (short)f2bf(x);
    }
    *(short8v*)(WN + (size_t)g * 8) = v;
  } else if (gid < 26624) {               // WP
    int g = gid - 24576;
    int lane = g & 63, nt = g >> 6;
    int col = nt*16 + (lane & 15);
    int k0  = (lane >> 4) * 8;
    float g1 = gateq[1];
    short8v v;
    #pragma unroll
    for (int j = 0; j < 8; ++j) {
      int k = k0 + j;
      float x = 0.f;
      if (k < 10)  x = g1 * ((col < 256) ? Wpos[(size_t)k*256 + col]
                                         : Wpos[(size_t)(10+k)*256 + (col-256)]);
      else if (k == 10 && col < 256) x = g1 * bpos[col];
      v[j] = (short)f2bf(x);
    }
    *(short8v*)(WP + (size_t)g * 8) = v;
  } else {                                // MW
    int g = gid - 26624;
    if (g >= 17*256) return;
    int row = g >> 8, col = g & 255;
    float x = 0.f;
    if (row > 0) {
      float a = 0.f;
      for (int k = 0; k < 64; ++k)
        a = fmaf(motif[(size_t)row*64 + k], Wstr[(size_t)(256+k)*256 + col], a);
      x = gateq[2] * a;
    }
    MW[g] = f2bf(x);
  }
}

// ---------------- node tables + S ----------------
// blocks [0, nNodeBlk): per node n (ALL N nodes):
//   TH[n] = [ g0*(x_n@Wnb_top + b_nb) | g1*(pos_n@Wpos_h + b_pos) ]  (512 bf16)
//   TT[n] = [ g0*(x_n@Wnb_bot)        | g1*(pos_n@Wpos_t)         ]
// blocks [nNodeBlk, +1000): S rows = g2*(rel @ W_str_top + b_str) (f32).
__global__ __launch_bounds__(512) void k_node_S(const float* __restrict__ ent,
                                                const float* __restrict__ ntx,
                                                const u16* __restrict__ WN,
                                                const u16* __restrict__ WP,
                                                u16* __restrict__ THg, u16* __restrict__ TTg,
                                                int NT, int N, int nNodeBlk,
                                                const float* __restrict__ rel,
                                                const float* __restrict__ Wstr,
                                                const float* __restrict__ b_nb,
                                                const float* __restrict__ b_str,
                                                const float* __restrict__ gateq,
                                                const float* __restrict__ pos,
                                                float* __restrict__ S) {
  const int t = threadIdx.x;
  if ((int)blockIdx.x >= nNodeBlk) {
    __shared__ float rs[2][256];
    int half = t >> 8, tc = t & 255;
    int r = (blockIdx.x - nNodeBlk) * 2 + half;
    rs[half][tc] = rel[(size_t)r*256 + tc];
    __syncthreads();
    float a = 0.f;
    for (int k = 0; k < 256; ++k) a = fmaf(rs[half][k], Wstr[(size_t)k*256 + tc], a);
    S[(size_t)r*256 + tc] = gateq[2] * (a + b_str[tc]);
    return;
  }
  __shared__ __align__(16) u16 AF[4*64*8];
  __shared__ __align__(16) u16 TTs[64*512];
  const int wv = t >> 6, l = t & 63;
  const int lr = l & 15, lg = l >> 4;
  const int nb0 = blockIdx.x * 64;
  const float g0 = gateq[0];

  const int mt = t >> 7, half = (t >> 6) & 1, l2 = t & 63;
  int snode = nb0 + mt*16 + (l2 & 15); if (snode >= N) snode = N - 1;
  const float* srow = (snode < NT) ? (ent + (size_t)snode * EMB) : ntx;

  f32x4 acc[4][4];
  #pragma unroll
  for (int m = 0; m < 4; ++m)
    #pragma unroll
    for (int n = 0; n < 4; ++n) acc[m][n] = (f32x4){0.f,0.f,0.f,0.f};

  for (int kc = 0; kc < 8; ++kc) {
    {
      int k = kc*32 + (l2 >> 4)*8 + half*4;
      float4 a4 = *(const float4*)(srow + k);
      short4v v;
      v[0]=(short)f2bf(a4.x); v[1]=(short)f2bf(a4.y);
      v[2]=(short)f2bf(a4.z); v[3]=(short)f2bf(a4.w);
      *(short4v*)&AF[((mt*64 + l2)*8 + half*4)] = v;
    }
    __syncthreads();
    short8v bn[4], af[4];
    #pragma unroll
    for (int n = 0; n < 4; ++n)
      bn[n] = *(const short8v*)&WN[((size_t)(kc*32 + wv*4 + n)*64 + l)*8];
    #pragma unroll
    for (int m = 0; m < 4; ++m)
      af[m] = *(const short8v*)&AF[(m*64 + l)*8];
    #pragma unroll
    for (int m = 0; m < 4; ++m)
      #pragma unroll
      for (int n = 0; n < 4; ++n)
        acc[m][n] = __builtin_amdgcn_mfma_f32_16x16x32_bf16(af[m], bn[n], acc[m][n], 0, 0, 0);
    __syncthreads();
  }
  // nb tile -> stage -> global (TH[0:256], TT[0:256])
  #pragma unroll
  for (int m = 0; m < 4; ++m)
    #pragma unroll
    for (int n = 0; n < 4; ++n) {
      int col = wv*64 + n*16 + lr;
      float bias = (col < 256) ? b_nb[col] : 0.f;
      #pragma unroll
      for (int r2 = 0; r2 < 4; ++r2)
        TTs[(m*16 + lg*4 + r2)*512 + col] = f2bf(g0 * (acc[m][n][r2] + bias));
    }
  __syncthreads();
  #pragma unroll
  for (int p = 0; p < 8; ++p) {
    int idx = p*512 + t;
    int nrow = idx >> 6, col = (idx & 63)*8;
    int node = nb0 + nrow;
    if (node < N) {
      uint4 v = *(const uint4*)&TTs[nrow*512 + col];
      u16* dst = (col < 256) ? (THg + (size_t)node*512 + col)
                             : (TTg + (size_t)node*512 + (col-256));
      *(uint4*)dst = v;
    }
  }
  __syncthreads();
  // pos chunk: A = [pos rows | 1-bias-row | 0], B = WP
  {
    int k = (l2 >> 4)*8 + half*4;
    int node = nb0 + mt*16 + (l2 & 15); if (node >= N) node = N - 1;
    float vv[4];
    #pragma unroll
    for (int j = 0; j < 4; ++j) {
      int kk = k + j;
      vv[j] = (kk < 10) ? pos[(size_t)node*10 + kk] : (kk == 10 ? 1.f : 0.f);
    }
    short4v v;
    v[0]=(short)f2bf(vv[0]); v[1]=(short)f2bf(vv[1]);
    v[2]=(short)f2bf(vv[2]); v[3]=(short)f2bf(vv[3]);
    *(short4v*)&AF[((mt*64 + l2)*8 + half*4)] = v;
  }
  __syncthreads();
  #pragma unroll
  for (int m = 0; m < 4; ++m)
    #pragma unroll
    for (int n = 0; n < 4; ++n) acc[m][n] = (f32x4){0.f,0.f,0.f,0.f};
  {
    short8v bn[4], af[4];
    #pragma unroll
    for (int n = 0; n < 4; ++n)
      bn[n] = *(const short8v*)&WP[((size_t)(wv*4 + n)*64 + l)*8];
    #pragma unroll
    for (int m = 0; m < 4; ++m)
      af[m] = *(const short8v*)&AF[(m*64 + l)*8];
    #pragma unroll
    for (int m = 0; m < 4; ++m)
      #pragma unroll
      for (int n = 0; n < 4; ++n)
        acc[m][n] = __builtin_amdgcn_mfma_f32_16x16x32_bf16(af[m], bn[n], acc[m][n], 0, 0, 0);
  }
  // pos tile -> stage -> global (TH[256:512], TT[256:512]); g1+bias folded in WP
  #pragma unroll
  for (int m = 0; m < 4; ++m)
    #pragma unroll
    for (int n = 0; n < 4; ++n) {
      int col = wv*64 + n*16 + lr;
      #pragma unroll
      for (int r2 = 0; r2 < 4; ++r2)
        TTs[(m*16 + lg*4 + r2)*512 + col] = f2bf(acc[m][n][r2]);
    }
  __syncthreads();
  #pragma unroll
  for (int p = 0; p < 8; ++p) {
    int idx = p*512 + t;
    int nrow = idx >> 6, col = (idx & 63)*8;
    int node = nb0 + nrow;
    if (node < N) {
      uint4 v = *(const uint4*)&TTs[nrow*512 + col];
      u16* dst = (col < 256) ? (THg + (size_t)node*512 + 256 + col)
                             : (TTg + (size_t)node*512 + 256 + (col-256));
      *(uint4*)dst = v;
    }
  }
}

// ---------------- main kernel: 64 edges/block, 4 waves ----------------
// Pure-gather fusion (no channel MFMA): fused = relu(THnb+TTnb) + relu(THpos+TTpos)
// + relu(S + sum wt*MW[id]); then layer1 (8 MFMA chunks) + layer2. TWO barriers total.
__global__ __launch_bounds__(256, 4)
void k_main(
    const int* __restrict__ h_id, const int* __restrict__ r_id, const int* __restrict__ t_id,
    const int* __restrict__ mids, const float* __restrict__ mwts,
    const float* __restrict__ W2, const float* __restrict__ b2,
    const float* __restrict__ gateq,
    const u16* __restrict__ WB, const float* __restrict__ S,
    const u16* __restrict__ MW,
    const u16* __restrict__ TH, const u16* __restrict__ TT,
    float* __restrict__ out, int E)
{
  __shared__ __align__(16) u16 FT2[8*4*64*8];   // fused [k=256][edge=64] frag order (32 KB)
  __shared__ float woacc[2][64];

  const int t  = threadIdx.x;
  const int wv = t >> 6, l = t & 63;
  const int Mw = wv >> 1, Nw = wv & 1;
  const int lr = l & 15, lg = l >> 4;
  const int be = blockIdx.x * 64;
  const int c  = t & 63;

  int eo = be + c; if (eo >= E) eo = E - 1;
  const int h = h_id[eo], td = t_id[eo], r = r_id[eo];
  const u16*   thp = TH + (size_t)h  * 512;
  const u16*   ttp = TT + (size_t)td * 512;
  const float* sp  = S  + (size_t)r  * 256;

  int4   mi0 = *(const int4*)  (mids + (size_t)eo*8);
  int4   mi1 = *(const int4*)  (mids + (size_t)eo*8 + 4);
  float4 mw0 = *(const float4*)(mwts + (size_t)eo*8);
  float4 mw1 = *(const float4*)(mwts + (size_t)eo*8 + 4);
  int   idv[8] = {mi0.x,mi0.y,mi0.z,mi0.w,mi1.x,mi1.y,mi1.z,mi1.w};
  float wtv[8] = {mw0.x,mw0.y,mw0.z,mw0.w,mw1.x,mw1.y,mw1.z,mw1.w};

  const int ob = (t >> 6) * 8;   // this thread's first k-octet

  #pragma unroll 1
  for (int i = 0; i < 8; ++i) {
    const int o = ob + i, k0 = o * 8;
    short8v anb = *(const short8v*)(thp + k0);
    short8v apo = *(const short8v*)(thp + 256 + k0);
    short8v bnb = *(const short8v*)(ttp + k0);
    short8v bpo = *(const short8v*)(ttp + 256 + k0);
    float4 sa = *(const float4*)(sp + k0);
    float4 sb = *(const float4*)(sp + k0 + 4);
    float sv[8] = {sa.x,sa.y,sa.z,sa.w,sb.x,sb.y,sb.z,sb.w};
    float mot[8] = {0,0,0,0,0,0,0,0};
    #pragma unroll
    for (int j = 0; j < 8; ++j) {
      short8v m8 = *(const short8v*)(MW + (size_t)idv[j]*256 + k0);  // MW[0] = 0
      float wj = wtv[j];
      #pragma unroll
      for (int e = 0; e < 8; ++e) mot[e] = fmaf(bf2f((u16)m8[e]), wj, mot[e]);
    }
    short8v w;
    #pragma unroll
    for (int e = 0; e < 8; ++e) {
      float f = fmaxf(bf2f((u16)anb[e]) + bf2f((u16)bnb[e]), 0.f)
              + fmaxf(bf2f((u16)apo[e]) + bf2f((u16)bpo[e]), 0.f)
              + fmaxf(sv[e] + mot[e], 0.f);
      w[e] = (short)f2bf(f);
    }
    *(short8v*)&FT2[(size_t)(((o >> 2)*4 + (c >> 4))*64 + (o & 3)*16 + (c & 15)) * 8] = w;
  }

  // ===== layer 1: acc init = qpart, B = FT2, A = WB chunks 0..7 =====
  f32x4 acc[8][2];
  #pragma unroll
  for (int m = 0; m < 8; ++m) {
    int f0 = Mw*128 + m*16 + lg*4;
    float4 q4 = *(const float4*)&gateq[4 + f0];
    f32x4 qv = { q4.x, q4.y, q4.z, q4.w };
    acc[m][0] = qv; acc[m][1] = qv;
  }
  __syncthreads();
  for (int c2 = 0; c2 < 8; ++c2) {
    const u16* wc = WB + (size_t)c2 * 8192;
    short8v bfr[2];
    #pragma unroll
    for (int n = 0; n < 2; ++n)
      bfr[n] = *(const short8v*)&FT2[((c2*4 + Nw*2 + n)*64 + l)*8];
    #pragma unroll
    for (int mh = 0; mh < 8; mh += 4) {
      short8v af[4];
      #pragma unroll
      for (int mm = 0; mm < 4; ++mm)
        af[mm] = *(const short8v*)&wc[((Mw*8 + mh + mm)*64 + l)*8];
      #pragma unroll
      for (int mm = 0; mm < 4; ++mm)
        #pragma unroll
        for (int n = 0; n < 2; ++n)
          acc[mh+mm][n] = __builtin_amdgcn_mfma_f32_16x16x32_bf16(af[mm], bfr[n], acc[mh+mm][n], 0, 0, 0);
    }
  }

  // ===== layer 2 =====
  {
    #pragma unroll
    for (int n = 0; n < 2; ++n) {
      float p = 0.f;
      #pragma unroll
      for (int m = 0; m < 8; ++m) {
        int f0 = Mw*128 + m*16 + lg*4;
        float4 w4 = *(const float4*)&W2[f0];
        p = fmaf(fmaxf(acc[m][n][0], 0.f), w4.x, p);
        p = fmaf(fmaxf(acc[m][n][1], 0.f), w4.y, p);
        p = fmaf(fmaxf(acc[m][n][2], 0.f), w4.z, p);
        p = fmaf(fmaxf(acc[m][n][3], 0.f), w4.w, p);
      }
      p += __shfl_xor(p, 16);
      p += __shfl_xor(p, 32);
      if (lg == 0) woacc[Mw][Nw*32 + n*16 + lr] = p;
    }
  }
  __syncthreads();
  if (t < 64) {
    int e = be + t;
    if (e < E)
      out[e] = woacc[0][t] + woacc[1][t] + b2[0];
  }
}

extern "C" void kernel_launch(void* const* d_in, const int* in_sizes, int n_in,
                              void* d_out, int out_size, void* d_ws, size_t ws_size,
                              hipStream_t stream) {
  const int*   h_id  = (const int*)  d_in[0];
  const int*   r_id  = (const int*)  d_in[1];
  const int*   t_id  = (const int*)  d_in[2];
  const float* q     = (const float*)d_in[3];
  const float* ent   = (const float*)d_in[4];
  const float* rel   = (const float*)d_in[6];
  const float* topic = (const float*)d_in[7];
  const int*   mids  = (const int*)  d_in[8];
  const float* mwts  = (const float*)d_in[9];
  const float* ntx   = (const float*)d_in[10];
  const float* motif = (const float*)d_in[11];
  const float* W_nb  = (const float*)d_in[12];
  const float* b_nb  = (const float*)d_in[13];
  const float* W_pos = (const float*)d_in[14];
  const float* b_pos = (const float*)d_in[15];
  const float* W_str = (const float*)d_in[16];
  const float* b_str = (const float*)d_in[17];
  const float* W_g   = (const float*)d_in[18];
  const float* b_g   = (const float*)d_in[19];
  const float* W1    = (const float*)d_in[20];
  const float* b1    = (const float*)d_in[21];
  const float* W2    = (const float*)d_in[22];
  const float* b2    = (const float*)d_in[23];
  float* out = (float*)d_out;

  const int E  = in_sizes[0];
  const int NT = in_sizes[4] / EMB;   // 80000 text entities
  const int N  = in_sizes[7] / 2;     // 100000 total nodes

  float* ws    = (float*)d_ws;
  float* cnt_f = ws;
  float* cnt_r = ws + (size_t)N;
  float* a1f   = ws + (size_t)2*N;
  float* a1r   = ws + (size_t)4*N;
  float* a2f   = ws + (size_t)6*N;
  float* a2r   = ws + (size_t)8*N;
  float* pos   = ws + (size_t)10*N;             // N x 10
  float* gateq = ws + (size_t)20*N;             // [g0,g1,g2,pad, qpart(256)]
  u16*   WB    = (u16*)(ws + (size_t)20*N + 512);   // 8*8192 u16
  u16*   WN    = WB + 65536;                        // 131072 u16
  u16*   WP    = WN + 131072;                       // 16384 u16
  u16*   MW    = WP + 16384;                        // 4352 (pad 4608) u16
  float* S     = (float*)(MW + 4608);               // 2000*256 f32
  u16*   THg   = (u16*)(S + (size_t)2000*256);      // N x 512 bf16
  u16*   TTg   = THg + (size_t)N*512;               // N x 512 bf16

  hipMemsetAsync(d_ws, 0, (size_t)10 * N * sizeof(float), stream);

  int gE = (E + 255) / 256, gN = (N + 255) / 256;
  int nNodeBlk = (N + 63) / 64;
  k_scatter1 <<<gE, 256, 0, stream>>>(h_id, t_id, topic, cnt_f, cnt_r, a1f, a1r, E);
  k_div1_gate<<<gN + 1, 256, 0, stream>>>(topic, cnt_f, cnt_r, a1f, a1r, pos, N,
                                          q, W_g, b_g, W1, b1, gateq);
  k_scatter2 <<<gE, 256, 0, stream>>>(h_id, t_id, pos, a2f, a2r, E);
  k_div2     <<<gN, 256, 0, stream>>>(cnt_f, cnt_r, a2f, a2r, pos, N);
  k_wtrans   <<<122, 256, 0, stream>>>(W_pos, W_str, W1, W_nb, b_pos, motif, gateq,
                                       WB, WN, WP, MW);
  k_node_S   <<<nNodeBlk + 1000, 512, 0, stream>>>(ent, ntx, WN, WP, THg, TTg,
                                                   NT, N, nNodeBlk,
                                                   rel, W_str, b_nb, b_str, gateq, pos, S);

  int gM = (E + 63) / 64;
  k_main<<<gM, 256, 0, stream>>>(h_id, r_id, t_id, mids, mwts,
                                 W2, b2, gateq, WB, S, MW, THg, TTg, out, E);
}

// Round 13
// 333.541 us; speedup vs baseline: 3.1333x; 3.1333x over previous
//
#include <hip/hip_runtime.h>

#define EMB 256
typedef unsigned short u16;
typedef __attribute__((ext_vector_type(8))) short short8v;
typedef __attribute__((ext_vector_type(4))) short short4v;
typedef __attribute__((ext_vector_type(4))) float f32x4;

__device__ inline u16 f2bf(float x){
  union{float f; unsigned u;} c; c.f = x;
  unsigned r = c.u + 0x7FFFu + ((c.u>>16)&1u);
  return (u16)(r>>16);
}
__device__ inline float bf2f(u16 h){
  union{unsigned u; float f;} c; c.u = ((unsigned)h) << 16; return c.f;
}

// ---------------- DDE: counts + round-1 scatter fused ----------------
__global__ void k_scatter1(const int* __restrict__ h_id, const int* __restrict__ t_id,
                           const float* __restrict__ topic,
                           float* __restrict__ cnt_f, float* __restrict__ cnt_r,
                           float* __restrict__ accf, float* __restrict__ accr, int E) {
  int e = blockIdx.x * 256 + threadIdx.x;
  if (e >= E) return;
  int h = h_id[e], t = t_id[e];
  atomicAdd(&cnt_f[t], 1.0f);
  atomicAdd(&cnt_r[h], 1.0f);
  float a0 = topic[2*h+0], a1 = topic[2*h+1];
  if (a0 != 0.f) atomicAdd(&accf[2*t+0], a0);
  if (a1 != 0.f) atomicAdd(&accf[2*t+1], a1);
  float c0 = topic[2*t+0], c1 = topic[2*t+1];
  if (c0 != 0.f) atomicAdd(&accr[2*h+0], c0);
  if (c1 != 0.f) atomicAdd(&accr[2*h+1], c1);
}

// block 0: gate softmax + qpart; blocks 1..gN: div1
__global__ void k_div1_gate(const float* __restrict__ topic,
                            const float* __restrict__ cnt_f, const float* __restrict__ cnt_r,
                            const float* __restrict__ accf, const float* __restrict__ accr,
                            float* __restrict__ pos, int N,
                            const float* __restrict__ q, const float* __restrict__ Wg,
                            const float* __restrict__ bg, const float* __restrict__ W1,
                            const float* __restrict__ b1, float* __restrict__ gateq) {
  int t = threadIdx.x;
  if (blockIdx.x == 0) {
    __shared__ float qs[256];
    __shared__ float z[3];
    qs[t] = q[t];
    __syncthreads();
    if (t < 3) {
      float s = bg[t];
      for (int k = 0; k < 256; ++k) s += qs[k] * Wg[k*3 + t];
      z[t] = s;
    }
    __syncthreads();
    if (t == 0) {
      float m = fmaxf(z[0], fmaxf(z[1], z[2]));
      float e0 = expf(z[0]-m), e1 = expf(z[1]-m), e2 = expf(z[2]-m);
      float s = e0 + e1 + e2;
      gateq[0] = e0/s; gateq[1] = e1/s; gateq[2] = e2/s; gateq[3] = 0.f;
    }
    float a = b1[t];
    for (int k = 0; k < 256; ++k) a += qs[k] * W1[k*256 + t];
    gateq[4 + t] = a;
    return;
  }
  int n = (blockIdx.x - 1) * 256 + t;
  if (n >= N) return;
  float cf = fmaxf(cnt_f[n], 1.0f), cr = fmaxf(cnt_r[n], 1.0f);
  pos[10*n+0] = topic[2*n+0];
  pos[10*n+1] = topic[2*n+1];
  pos[10*n+2] = accf[2*n+0] / cf;
  pos[10*n+3] = accf[2*n+1] / cf;
  pos[10*n+6] = accr[2*n+0] / cr;
  pos[10*n+7] = accr[2*n+1] / cr;
}

__global__ void k_scatter2(const int* __restrict__ h_id, const int* __restrict__ t_id,
                           const float* __restrict__ pos,
                           float* __restrict__ accf, float* __restrict__ accr, int E) {
  int e = blockIdx.x * 256 + threadIdx.x;
  if (e >= E) return;
  int h = h_id[e], t = t_id[e];
  float a0 = pos[10*h+2], a1 = pos[10*h+3];
  if (a0 != 0.f) atomicAdd(&accf[2*t+0], a0);
  if (a1 != 0.f) atomicAdd(&accf[2*t+1], a1);
  float c0 = pos[10*t+6], c1 = pos[10*t+7];
  if (c0 != 0.f) atomicAdd(&accr[2*h+0], c0);
  if (c1 != 0.f) atomicAdd(&accr[2*h+1], c1);
}

__global__ void k_div2(const float* __restrict__ cnt_f, const float* __restrict__ cnt_r,
                       const float* __restrict__ accf, const float* __restrict__ accr,
                       float* __restrict__ pos, int N) {
  int n = blockIdx.x * 256 + threadIdx.x;
  if (n >= N) return;
  float cf = fmaxf(cnt_f[n], 1.0f), cr = fmaxf(cnt_r[n], 1.0f);
  pos[10*n+4] = accf[2*n+0] / cf;
  pos[10*n+5] = accf[2*n+1] / cf;
  pos[10*n+8] = accr[2*n+0] / cr;
  pos[10*n+9] = accr[2*n+1] / cr;
}

// ---------------- weight transforms (gate-folded) ----------------
// WB A-frag chunks (10 x K=32): [0]=g1*W_pos(20 rows)+bias-row k=20,
// [1]=WM motif: A[f][m] = g2 * motif[m]@Wstr[256:320][:,f] (m in 1..16; 0 else),
// [2..9]=W1[256:512]. WN: B-frags for k_node nb GEMM, cols=[Wnb_top|Wnb_bot].
__global__ void k_wtrans(const float* __restrict__ Wpos, const float* __restrict__ Wstr,
                         const float* __restrict__ W1, const float* __restrict__ Wnb,
                         const float* __restrict__ bpos, const float* __restrict__ motif,
                         const float* __restrict__ gateq,
                         u16* __restrict__ WB, u16* __restrict__ WN) {
  int gid = blockIdx.x * 256 + threadIdx.x;
  if (gid < 10*1024) {
    int lane = gid & 63, ft = (gid >> 6) & 15, kt = gid >> 10;
    int n  = ft*16 + (lane & 15);
    int k0 = (lane >> 4) * 8;
    short8v v;
    if (kt == 0) {
      float g1 = gateq[1];
      #pragma unroll
      for (int j = 0; j < 8; ++j) {
        int k = k0 + j;
        float x = (k < 20) ? g1 * Wpos[(size_t)k*256 + n]
                : (k == 20) ? g1 * bpos[n] : 0.f;
        v[j] = (short)f2bf(x);
      }
    } else if (kt == 1) {
      float g2 = gateq[2];
      #pragma unroll
      for (int j = 0; j < 8; ++j) {
        int m = k0 + j;
        float x = 0.f;
        if (m >= 1 && m < 17) {
          float a = 0.f;
          for (int k = 0; k < 64; ++k)
            a = fmaf(motif[(size_t)m*64 + k], Wstr[(size_t)(256+k)*256 + n], a);
          x = g2 * a;
        }
        v[j] = (short)f2bf(x);
      }
    } else {
      int kb = (kt - 2) * 32;
      #pragma unroll
      for (int j = 0; j < 8; ++j)
        v[j] = (short)f2bf(W1[(size_t)(256 + kb + k0 + j)*256 + n]);
    }
    *(short8v*)(WB + (size_t)gid * 8) = v;
  } else {
    int g = gid - 10240;
    if (g >= 8*32*64) return;
    int lane = g & 63, nt = (g >> 6) & 31, kc = g >> 11;
    int col = nt*16 + (lane & 15);
    int k0  = kc*32 + (lane >> 4) * 8;
    short8v v;
    #pragma unroll
    for (int j = 0; j < 8; ++j) {
      int k = k0 + j;
      float x = (col < 256) ? Wnb[(size_t)k*256 + col] : Wnb[(size_t)(256+k)*256 + (col-256)];
      v[j] = (short)f2bf(x);
    }
    *(short8v*)(WN + (size_t)g * 8) = v;
  }
}

// ---------------- node tables + S (gate/bias-folded) ----------------
// blocks [0,nNodeBlk): TA[n]=g0*(x_n@Wnb_top+b_nb), TB[n]=g0*(x_n@Wnb_bot), bf16 256/row.
// blocks [nNodeBlk,+1000): S rows = g2*(rel @ W_str_top + b_str) (f32).
__global__ __launch_bounds__(512) void k_node_S(const float* __restrict__ ent,
                                                const float* __restrict__ ntx,
                                                const u16* __restrict__ WN,
                                                u16* __restrict__ TA, u16* __restrict__ TB,
                                                int NT, int nNodeBlk,
                                                const float* __restrict__ rel,
                                                const float* __restrict__ Wstr,
                                                const float* __restrict__ b_nb,
                                                const float* __restrict__ b_str,
                                                const float* __restrict__ gateq,
                                                float* __restrict__ S) {
  const int t = threadIdx.x;
  if ((int)blockIdx.x >= nNodeBlk) {
    __shared__ float rs[2][256];
    int half = t >> 8, tc = t & 255;
    int r = (blockIdx.x - nNodeBlk) * 2 + half;
    rs[half][tc] = rel[(size_t)r*256 + tc];
    __syncthreads();
    float a = 0.f;
    for (int k = 0; k < 256; ++k) a = fmaf(rs[half][k], Wstr[(size_t)k*256 + tc], a);
    S[(size_t)r*256 + tc] = gateq[2] * (a + b_str[tc]);
    return;
  }
  __shared__ __align__(16) u16 AF[4*64*8];
  __shared__ __align__(16) u16 TT[64*512];
  const int wv = t >> 6, l = t & 63;
  const int lr = l & 15, lg = l >> 4;
  const int nb0 = blockIdx.x * 64;
  const float g0 = gateq[0];

  const int mt = t >> 7, half = (t >> 6) & 1, l2 = t & 63;
  int snode = nb0 + mt*16 + (l2 & 15);
  const float* srow = (snode < NT) ? (ent + (size_t)snode * EMB) : ntx;

  f32x4 acc[4][4];
  #pragma unroll
  for (int m = 0; m < 4; ++m)
    #pragma unroll
    for (int n = 0; n < 4; ++n) acc[m][n] = (f32x4){0.f,0.f,0.f,0.f};

  for (int kc = 0; kc < 8; ++kc) {
    {
      int k = kc*32 + (l2 >> 4)*8 + half*4;
      float4 a4 = *(const float4*)(srow + k);
      short4v v;
      v[0]=(short)f2bf(a4.x); v[1]=(short)f2bf(a4.y);
      v[2]=(short)f2bf(a4.z); v[3]=(short)f2bf(a4.w);
      *(short4v*)&AF[((mt*64 + l2)*8 + half*4)] = v;
    }
    __syncthreads();
    short8v bn[4], af[4];
    #pragma unroll
    for (int n = 0; n < 4; ++n)
      bn[n] = *(const short8v*)&WN[((size_t)(kc*32 + wv*4 + n)*64 + l)*8];
    #pragma unroll
    for (int m = 0; m < 4; ++m)
      af[m] = *(const short8v*)&AF[(m*64 + l)*8];
    #pragma unroll
    for (int m = 0; m < 4; ++m)
      #pragma unroll
      for (int n = 0; n < 4; ++n)
        acc[m][n] = __builtin_amdgcn_mfma_f32_16x16x32_bf16(af[m], bn[n], acc[m][n], 0, 0, 0);
    __syncthreads();
  }
  #pragma unroll
  for (int m = 0; m < 4; ++m)
    #pragma unroll
    for (int n = 0; n < 4; ++n) {
      int col = wv*64 + n*16 + lr;
      float bias = (col < 256) ? b_nb[col] : 0.f;
      #pragma unroll
      for (int r2 = 0; r2 < 4; ++r2)
        TT[(m*16 + lg*4 + r2)*512 + col] = f2bf(g0 * (acc[m][n][r2] + bias));
    }
  __syncthreads();
  #pragma unroll
  for (int p = 0; p < 8; ++p) {
    int idx = p*512 + t;
    int nrow = idx >> 6, col = (idx & 63)*8;
    int node = nb0 + nrow;
    if (node <= NT) {
      uint4 v = *(const uint4*)&TT[nrow*512 + col];
      u16* dst = (col < 256) ? (TA + (size_t)node*256 + col)
                             : (TB + (size_t)node*256 + (col-256));
      *(uint4*)dst = v;
    }
  }
}

// ---------------- main kernel: 64 edges/block, 4 waves, 3 barriers ----------------
__global__ __launch_bounds__(256, 4)
void k_main(
    const int* __restrict__ h_id, const int* __restrict__ r_id, const int* __restrict__ t_id,
    const int* __restrict__ mids, const float* __restrict__ mwts,
    const float* __restrict__ W2, const float* __restrict__ b2,
    const float* __restrict__ pos, const float* __restrict__ gateq,
    const u16* __restrict__ WB, const float* __restrict__ S,
    const u16* __restrict__ TA, const u16* __restrict__ TB,
    float* __restrict__ out, int E, int NT)
{
  __shared__ __align__(16) u16 SH[20480];   // 40960 B total
  u16* FT2 = SH;                             // 32 KB: [kc][nt][64][8]
  u16* XB  = SH + 16384;                     // 4 KB: pos B-chunk
  u16* XB2 = SH + 18432;                     // 4 KB: motif-vec B-chunk
  float* woacc = (float*)(SH + 16384);       // aliases XB (dead by then)

  const int t  = threadIdx.x;
  const int wv = t >> 6, l = t & 63;
  const int Mw = wv >> 1, Nw = wv & 1;
  const int lr = l & 15, lg = l >> 4;
  const int be = blockIdx.x * 64;

  int eo = be + wv*16 + lr; if (eo >= E) eo = E - 1;
  const int hid = h_id[eo], tid = t_id[eo];

  // ===== A1: TA gathers async -> FT2 (wave-uniform dst, line-efficient src) =====
  {
    const int hc = (hid < NT) ? hid : NT;
    const u16* paw = TA + (size_t)hc*256 + lg*8;
    #pragma unroll
    for (int kc = 0; kc < 8; ++kc)
      __builtin_amdgcn_global_load_lds(
        (const __attribute__((address_space(1))) unsigned int*)(paw + kc*32),
        (__attribute__((address_space(3))) unsigned int*)&FT2[kc*2048 + wv*512],
        16, 0, 0);
  }

  // ===== A2: pos -> XB (k==20 -> 1.0 bias row) =====
  {
    float vals[8];
    #pragma unroll
    for (int jp = 0; jp < 4; ++jp) {
      int k2 = lg*8 + jp*2;
      float2 f2;
      if (k2 < 10)       f2 = *(const float2*)&pos[(size_t)hid*10 + k2];
      else if (k2 < 20)  f2 = *(const float2*)&pos[(size_t)tid*10 + (k2 - 10)];
      else if (k2 == 20) f2 = make_float2(1.f, 0.f);
      else               f2 = make_float2(0.f, 0.f);
      vals[jp*2] = f2.x; vals[jp*2+1] = f2.y;
    }
    short8v v;
    #pragma unroll
    for (int j = 0; j < 8; ++j) v[j] = (short)f2bf(vals[j]);
    *(short8v*)&XB[(wv*64 + l)*8] = v;
  }

  // ===== A3: motif weight-vector -> XB2 (v[m] = sum of wts with id==m; WM[0]=0) =====
  {
    int4   mi0 = *(const int4*)  (mids + (size_t)eo*8);
    int4   mi1 = *(const int4*)  (mids + (size_t)eo*8 + 4);
    float4 mw0 = *(const float4*)(mwts + (size_t)eo*8);
    float4 mw1 = *(const float4*)(mwts + (size_t)eo*8 + 4);
    int   idv[8] = {mi0.x,mi0.y,mi0.z,mi0.w,mi1.x,mi1.y,mi1.z,mi1.w};
    float wtv[8] = {mw0.x,mw0.y,mw0.z,mw0.w,mw1.x,mw1.y,mw1.z,mw1.w};
    float s[8] = {0,0,0,0,0,0,0,0};
    #pragma unroll
    for (int j = 0; j < 8; ++j)
      #pragma unroll
      for (int i = 0; i < 8; ++i)
        s[i] += (idv[j] == lg*8 + i) ? wtv[j] : 0.f;
    short8v v;
    #pragma unroll
    for (int i = 0; i < 8; ++i) v[i] = (short)f2bf(s[i]);
    *(short8v*)&XB2[(wv*64 + l)*8] = v;
  }

  // ===== A4: nb channel: TB via regs, TA from LDS; FT2 = relu(ta+tb) =====
  {
    const int tc2 = (tid < NT) ? tid : NT;
    const u16* pbw = TB + (size_t)tc2*256 + lg*8;
    short8v tb0 = *(const short8v*)(pbw);
    short8v tb1 = *(const short8v*)(pbw + 32);
    asm volatile("s_waitcnt vmcnt(0)" ::: "memory");
    __builtin_amdgcn_sched_barrier(0);
    #pragma unroll
    for (int kk = 0; kk < 8; kk += 2) {
      short8v nba = tb0, nbb = tb1;
      if (kk < 6) {
        tb0 = *(const short8v*)(pbw + (kk+2)*32);
        tb1 = *(const short8v*)(pbw + (kk+3)*32);
      }
      #pragma unroll
      for (int c2 = 0; c2 < 2; ++c2) {
        short8v nb = c2 ? nbb : nba;
        u16* slot = &FT2[((kk+c2)*4 + wv)*512 + l*8];
        short8v o = *(const short8v*)slot;
        short8v w;
        #pragma unroll
        for (int j = 0; j < 8; ++j)
          w[j] = (short)f2bf(fmaxf(bf2f((u16)o[j]) + bf2f((u16)nb[j]), 0.f));
        *(short8v*)slot = w;
      }
    }
  }

  f32x4 acc[8][2];
  auto zacc = [&]() {
    #pragma unroll
    for (int m = 0; m < 8; ++m)
      #pragma unroll
      for (int n = 0; n < 2; ++n) acc[m][n] = (f32x4){0.f,0.f,0.f,0.f};
  };
  auto mfma_chunk = [&](const u16* wc, const u16* xb) {
    short8v bfr[2];
    #pragma unroll
    for (int n = 0; n < 2; ++n)
      bfr[n] = *(const short8v*)&xb[((Nw*2 + n)*64 + l)*8];
    #pragma unroll
    for (int mh = 0; mh < 8; mh += 4) {
      short8v af[4];
      #pragma unroll
      for (int mm = 0; mm < 4; ++mm)
        af[mm] = *(const short8v*)&wc[((Mw*8 + mh + mm)*64 + l)*8];
      #pragma unroll
      for (int mm = 0; mm < 4; ++mm)
        #pragma unroll
        for (int n = 0; n < 2; ++n)
          acc[mh+mm][n] = __builtin_amdgcn_mfma_f32_16x16x32_bf16(af[mm], bfr[n], acc[mh+mm][n], 0, 0, 0);
    }
  };

  zacc();
  __syncthreads();                 // barrier 1: FT2 nb + XB + XB2 visible

  // ===== B1: pos MFMA + RMW combine =====
  mfma_chunk(WB, XB);
  {
    #pragma unroll
    for (int m = 0; m < 8; ++m) {
      int kc  = Mw*4 + ((m*4 + lg) >> 3);
      int lg2 = (m*2 + (lg >> 1)) & 3;
      #pragma unroll
      for (int n = 0; n < 2; ++n) {
        int nt = Nw*2 + n;
        int idx = ((kc*4 + nt)*64 + lg2*16 + lr)*8 + (lg & 1)*4;
        short4v o = *(const short4v*)&FT2[idx];
        short4v w;
        w[0] = (short)f2bf(bf2f((u16)o[0]) + fmaxf(acc[m][n][0], 0.f));
        w[1] = (short)f2bf(bf2f((u16)o[1]) + fmaxf(acc[m][n][1], 0.f));
        w[2] = (short)f2bf(bf2f((u16)o[2]) + fmaxf(acc[m][n][2], 0.f));
        w[3] = (short)f2bf(bf2f((u16)o[3]) + fmaxf(acc[m][n][3], 0.f));
        *(short4v*)&FT2[idx] = w;
      }
    }
  }
  zacc();

  // ===== B2: motif MFMA (XB2, staged pre-barrier) + struct combine (same slots) =====
  mfma_chunk(WB + 8192, XB2);
  {
    int r0 = be + (Nw*2 + 0)*16 + lr; if (r0 >= E) r0 = E - 1;
    int r1 = be + (Nw*2 + 1)*16 + lr; if (r1 >= E) r1 = E - 1;
    int rr[2] = { r_id[r0], r_id[r1] };
    #pragma unroll
    for (int m = 0; m < 8; ++m) {
      int f0 = Mw*128 + m*16 + lg*4;
      int kc  = Mw*4 + ((m*4 + lg) >> 3);
      int lg2 = (m*2 + (lg >> 1)) & 3;
      #pragma unroll
      for (int n = 0; n < 2; ++n) {
        int nt = Nw*2 + n;
        float4 sv = *(const float4*)&S[(size_t)rr[n]*256 + f0];
        int idx = ((kc*4 + nt)*64 + lg2*16 + lr)*8 + (lg & 1)*4;
        short4v o = *(const short4v*)&FT2[idx];
        short4v w;
        w[0] = (short)f2bf(bf2f((u16)o[0]) + fmaxf(acc[m][n][0] + sv.x, 0.f));
        w[1] = (short)f2bf(bf2f((u16)o[1]) + fmaxf(acc[m][n][1] + sv.y, 0.f));
        w[2] = (short)f2bf(bf2f((u16)o[2]) + fmaxf(acc[m][n][2] + sv.z, 0.f));
        w[3] = (short)f2bf(bf2f((u16)o[3]) + fmaxf(acc[m][n][3] + sv.w, 0.f));
        *(short4v*)&FT2[idx] = w;
      }
    }
  }

  // ===== C: layer 1 (acc init = qpart), A = WB chunks 2..9, B = FT2 =====
  #pragma unroll
  for (int m = 0; m < 8; ++m) {
    int f0 = Mw*128 + m*16 + lg*4;
    float4 q4 = *(const float4*)&gateq[4 + f0];
    f32x4 qv = { q4.x, q4.y, q4.z, q4.w };
    acc[m][0] = qv; acc[m][1] = qv;
  }
  __syncthreads();                 // barrier 2: FT2 final for cross-wave reads
  for (int c2 = 0; c2 < 8; ++c2) {
    const u16* wc = WB + (size_t)(2 + c2) * 8192;
    short8v bfr[2];
    #pragma unroll
    for (int n = 0; n < 2; ++n)
      bfr[n] = *(const short8v*)&FT2[((c2*4 + Nw*2 + n)*64 + l)*8];
    #pragma unroll
    for (int mh = 0; mh < 8; mh += 4) {
      short8v af[4];
      #pragma unroll
      for (int mm = 0; mm < 4; ++mm)
        af[mm] = *(const short8v*)&wc[((Mw*8 + mh + mm)*64 + l)*8];
      #pragma unroll
      for (int mm = 0; mm < 4; ++mm)
        #pragma unroll
        for (int n = 0; n < 2; ++n)
          acc[mh+mm][n] = __builtin_amdgcn_mfma_f32_16x16x32_bf16(af[mm], bfr[n], acc[mh+mm][n], 0, 0, 0);
    }
  }

  // ===== layer 2 =====
  {
    #pragma unroll
    for (int n = 0; n < 2; ++n) {
      float p = 0.f;
      #pragma unroll
      for (int m = 0; m < 8; ++m) {
        int f0 = Mw*128 + m*16 + lg*4;
        float4 w4 = *(const float4*)&W2[f0];
        p = fmaf(fmaxf(acc[m][n][0], 0.f), w4.x, p);
        p = fmaf(fmaxf(acc[m][n][1], 0.f), w4.y, p);
        p = fmaf(fmaxf(acc[m][n][2], 0.f), w4.z, p);
        p = fmaf(fmaxf(acc[m][n][3], 0.f), w4.w, p);
      }
      p += __shfl_xor(p, 16);
      p += __shfl_xor(p, 32);
      if (lg == 0) woacc[Mw*64 + Nw*32 + n*16 + lr] = p;
    }
  }
  __syncthreads();                 // barrier 3
  if (t < 64) {
    int e = be + t;
    if (e < E)
      out[e] = woacc[t] + woacc[64 + t] + b2[0];
  }
}

extern "C" void kernel_launch(void* const* d_in, const int* in_sizes, int n_in,
                              void* d_out, int out_size, void* d_ws, size_t ws_size,
                              hipStream_t stream) {
  const int*   h_id  = (const int*)  d_in[0];
  const int*   r_id  = (const int*)  d_in[1];
  const int*   t_id  = (const int*)  d_in[2];
  const float* q     = (const float*)d_in[3];
  const float* ent   = (const float*)d_in[4];
  const float* rel   = (const float*)d_in[6];
  const float* topic = (const float*)d_in[7];
  const int*   mids  = (const int*)  d_in[8];
  const float* mwts  = (const float*)d_in[9];
  const float* ntx   = (const float*)d_in[10];
  const float* motif = (const float*)d_in[11];
  const float* W_nb  = (const float*)d_in[12];
  const float* b_nb  = (const float*)d_in[13];
  const float* W_pos = (const float*)d_in[14];
  const float* b_pos = (const float*)d_in[15];
  const float* W_str = (const float*)d_in[16];
  const float* b_str = (const float*)d_in[17];
  const float* W_g   = (const float*)d_in[18];
  const float* b_g   = (const float*)d_in[19];
  const float* W1    = (const float*)d_in[20];
  const float* b1    = (const float*)d_in[21];
  const float* W2    = (const float*)d_in[22];
  const float* b2    = (const float*)d_in[23];
  float* out = (float*)d_out;

  const int E  = in_sizes[0];
  const int NT = in_sizes[4] / EMB;   // 80000 text entities
  const int N  = in_sizes[7] / 2;     // 100000 total nodes

  float* ws    = (float*)d_ws;
  float* cnt_f = ws;
  float* cnt_r = ws + (size_t)N;
  float* a1f   = ws + (size_t)2*N;
  float* a1r   = ws + (size_t)4*N;
  float* a2f   = ws + (size_t)6*N;
  float* a2r   = ws + (size_t)8*N;
  float* pos   = ws + (size_t)10*N;             // N x 10
  float* gateq = ws + (size_t)20*N;             // [g0,g1,g2,pad, qpart(256)]
  u16*   WB    = (u16*)(ws + (size_t)20*N + 512);   // 10*8192 u16
  u16*   WN    = WB + (size_t)10*8192;              // 131072 u16
  float* S     = (float*)(WN + 131072);             // 2000*256 f32
  u16*   TA    = (u16*)(S + (size_t)2000*256);      // (NT+1) x 256 bf16
  u16*   TB    = TA + (size_t)(NT+1)*256;

  hipMemsetAsync(d_ws, 0, (size_t)10 * N * sizeof(float), stream);

  int gE = (E + 255) / 256, gN = (N + 255) / 256;
  int nNodeBlk = (NT + 64) / 64;
  k_scatter1 <<<gE, 256, 0, stream>>>(h_id, t_id, topic, cnt_f, cnt_r, a1f, a1r, E);
  k_div1_gate<<<gN + 1, 256, 0, stream>>>(topic, cnt_f, cnt_r, a1f, a1r, pos, N,
                                          q, W_g, b_g, W1, b1, gateq);
  k_scatter2 <<<gE, 256, 0, stream>>>(h_id, t_id, pos, a2f, a2r, E);
  k_div2     <<<gN, 256, 0, stream>>>(cnt_f, cnt_r, a2f, a2r, pos, N);
  k_wtrans   <<<104, 256, 0, stream>>>(W_pos, W_str, W1, W_nb, b_pos, motif, gateq,
                                       WB, WN);
  k_node_S   <<<nNodeBlk + 1000, 512, 0, stream>>>(ent, ntx, WN, TA, TB, NT, nNodeBlk,
                                                   rel, W_str, b_nb, b_str, gateq, S);

  int gM = (E + 63) / 64;
  k_main<<<gM, 256, 0, stream>>>(h_id, r_id, t_id, mids, mwts,
                                 W2, b2, pos, gateq, WB, S, TA, TB, out, E, NT);
}

// Round 14
// 321.160 us; speedup vs baseline: 3.2541x; 1.0386x over previous
//
#include <hip/hip_runtime.h>

#define EMB 256
typedef unsigned short u16;
typedef __attribute__((ext_vector_type(8))) short short8v;
typedef __attribute__((ext_vector_type(4))) short short4v;
typedef __attribute__((ext_vector_type(4))) float f32x4;

__device__ inline u16 f2bf(float x){
  union{float f; unsigned u;} c; c.f = x;
  unsigned r = c.u + 0x7FFFu + ((c.u>>16)&1u);
  return (u16)(r>>16);
}
__device__ inline float bf2f(u16 h){
  union{unsigned u; float f;} c; c.u = ((unsigned)h) << 16; return c.f;
}
// packed bf16 pack/unpack (RNE, matches f2bf)
__device__ inline unsigned pk2(float a, float b){
  unsigned r;
  asm("v_cvt_pk_bf16_f32 %0, %1, %2" : "=v"(r) : "v"(a), "v"(b));
  return r;
}
__device__ inline void unpk(unsigned d, float& lo, float& hi){
  union{unsigned u; float f;} a, b;
  a.u = d << 16; b.u = d & 0xffff0000u;
  lo = a.f; hi = b.f;
}

// ---------------- DDE: counts + round-1 scatter fused ----------------
__global__ void k_scatter1(const int* __restrict__ h_id, const int* __restrict__ t_id,
                           const float* __restrict__ topic,
                           float* __restrict__ cnt_f, float* __restrict__ cnt_r,
                           float* __restrict__ accf, float* __restrict__ accr, int E) {
  int e = blockIdx.x * 256 + threadIdx.x;
  if (e >= E) return;
  int h = h_id[e], t = t_id[e];
  atomicAdd(&cnt_f[t], 1.0f);
  atomicAdd(&cnt_r[h], 1.0f);
  float a0 = topic[2*h+0], a1 = topic[2*h+1];
  if (a0 != 0.f) atomicAdd(&accf[2*t+0], a0);
  if (a1 != 0.f) atomicAdd(&accf[2*t+1], a1);
  float c0 = topic[2*t+0], c1 = topic[2*t+1];
  if (c0 != 0.f) atomicAdd(&accr[2*h+0], c0);
  if (c1 != 0.f) atomicAdd(&accr[2*h+1], c1);
}

// block 0: gate softmax + qpart; blocks 1..gN: div1
__global__ void k_div1_gate(const float* __restrict__ topic,
                            const float* __restrict__ cnt_f, const float* __restrict__ cnt_r,
                            const float* __restrict__ accf, const float* __restrict__ accr,
                            float* __restrict__ pos, int N,
                            const float* __restrict__ q, const float* __restrict__ Wg,
                            const float* __restrict__ bg, const float* __restrict__ W1,
                            const float* __restrict__ b1, float* __restrict__ gateq) {
  int t = threadIdx.x;
  if (blockIdx.x == 0) {
    __shared__ float qs[256];
    __shared__ float z[3];
    qs[t] = q[t];
    __syncthreads();
    if (t < 3) {
      float s = bg[t];
      for (int k = 0; k < 256; ++k) s += qs[k] * Wg[k*3 + t];
      z[t] = s;
    }
    __syncthreads();
    if (t == 0) {
      float m = fmaxf(z[0], fmaxf(z[1], z[2]));
      float e0 = expf(z[0]-m), e1 = expf(z[1]-m), e2 = expf(z[2]-m);
      float s = e0 + e1 + e2;
      gateq[0] = e0/s; gateq[1] = e1/s; gateq[2] = e2/s; gateq[3] = 0.f;
    }
    float a = b1[t];
    for (int k = 0; k < 256; ++k) a += qs[k] * W1[k*256 + t];
    gateq[4 + t] = a;
    return;
  }
  int n = (blockIdx.x - 1) * 256 + t;
  if (n >= N) return;
  float cf = fmaxf(cnt_f[n], 1.0f), cr = fmaxf(cnt_r[n], 1.0f);
  pos[10*n+0] = topic[2*n+0];
  pos[10*n+1] = topic[2*n+1];
  pos[10*n+2] = accf[2*n+0] / cf;
  pos[10*n+3] = accf[2*n+1] / cf;
  pos[10*n+6] = accr[2*n+0] / cr;
  pos[10*n+7] = accr[2*n+1] / cr;
}

__global__ void k_scatter2(const int* __restrict__ h_id, const int* __restrict__ t_id,
                           const float* __restrict__ pos,
                           float* __restrict__ accf, float* __restrict__ accr, int E) {
  int e = blockIdx.x * 256 + threadIdx.x;
  if (e >= E) return;
  int h = h_id[e], t = t_id[e];
  float a0 = pos[10*h+2], a1 = pos[10*h+3];
  if (a0 != 0.f) atomicAdd(&accf[2*t+0], a0);
  if (a1 != 0.f) atomicAdd(&accf[2*t+1], a1);
  float c0 = pos[10*t+6], c1 = pos[10*t+7];
  if (c0 != 0.f) atomicAdd(&accr[2*h+0], c0);
  if (c1 != 0.f) atomicAdd(&accr[2*h+1], c1);
}

// ---------------- weight transforms (gate-folded) ----------------
// WB A-frag chunks (10 x K=32): [0]=g1*W_pos(20 rows)+bias-row k=20,
// [1]=WM motif: A[f][m] = g2 * motif[m]@Wstr[256:320][:,f] (m in 1..16; 0 else),
// [2..9]=W1[256:512]. WN: B-frags for k_node nb GEMM, cols=[Wnb_top|Wnb_bot].
__global__ void k_wtrans(const float* __restrict__ Wpos, const float* __restrict__ Wstr,
                         const float* __restrict__ W1, const float* __restrict__ Wnb,
                         const float* __restrict__ bpos, const float* __restrict__ motif,
                         const float* __restrict__ gateq,
                         u16* __restrict__ WB, u16* __restrict__ WN) {
  int gid = blockIdx.x * 256 + threadIdx.x;
  if (gid < 10*1024) {
    int lane = gid & 63, ft = (gid >> 6) & 15, kt = gid >> 10;
    int n  = ft*16 + (lane & 15);
    int k0 = (lane >> 4) * 8;
    short8v v;
    if (kt == 0) {
      float g1 = gateq[1];
      #pragma unroll
      for (int j = 0; j < 8; ++j) {
        int k = k0 + j;
        float x = (k < 20) ? g1 * Wpos[(size_t)k*256 + n]
                : (k == 20) ? g1 * bpos[n] : 0.f;
        v[j] = (short)f2bf(x);
      }
    } else if (kt == 1) {
      float g2 = gateq[2];
      #pragma unroll
      for (int j = 0; j < 8; ++j) {
        int m = k0 + j;
        float x = 0.f;
        if (m >= 1 && m < 17) {
          float a = 0.f;
          for (int k = 0; k < 64; ++k)
            a = fmaf(motif[(size_t)m*64 + k], Wstr[(size_t)(256+k)*256 + n], a);
          x = g2 * a;
        }
        v[j] = (short)f2bf(x);
      }
    } else {
      int kb = (kt - 2) * 32;
      #pragma unroll
      for (int j = 0; j < 8; ++j)
        v[j] = (short)f2bf(W1[(size_t)(256 + kb + k0 + j)*256 + n]);
    }
    *(short8v*)(WB + (size_t)gid * 8) = v;
  } else {
    int g = gid - 10240;
    if (g >= 8*32*64) return;
    int lane = g & 63, nt = (g >> 6) & 31, kc = g >> 11;
    int col = nt*16 + (lane & 15);
    int k0  = kc*32 + (lane >> 4) * 8;
    short8v v;
    #pragma unroll
    for (int j = 0; j < 8; ++j) {
      int k = k0 + j;
      float x = (col < 256) ? Wnb[(size_t)k*256 + col] : Wnb[(size_t)(256+k)*256 + (col-256)];
      v[j] = (short)f2bf(x);
    }
    *(short8v*)(WN + (size_t)g * 8) = v;
  }
}

// ---------------- node tables + S + div2 tail (gate/bias-folded) ----------------
// blocks [0,nNodeBlk): TA[n]=g0*(x_n@Wnb_top+b_nb), TB[n]=g0*(x_n@Wnb_bot), bf16.
// blocks [nNodeBlk, +1000): S rows = g2*(rel @ W_str_top + b_str) (f32).
// blocks [nNodeBlk+1000, +gD): DDE div2 (pos cols 4,5,8,9).
__global__ __launch_bounds__(512) void k_node_S(const float* __restrict__ ent,
                                                const float* __restrict__ ntx,
                                                const u16* __restrict__ WN,
                                                u16* __restrict__ TA, u16* __restrict__ TB,
                                                int NT, int nNodeBlk,
                                                const float* __restrict__ rel,
                                                const float* __restrict__ Wstr,
                                                const float* __restrict__ b_nb,
                                                const float* __restrict__ b_str,
                                                const float* __restrict__ gateq,
                                                const float* __restrict__ cnt_f,
                                                const float* __restrict__ cnt_r,
                                                const float* __restrict__ a2f,
                                                const float* __restrict__ a2r,
                                                float* __restrict__ posw, int N,
                                                float* __restrict__ S) {
  const int t = threadIdx.x;
  if ((int)blockIdx.x >= nNodeBlk + 1000) {    // div2 tail
    int n = ((int)blockIdx.x - nNodeBlk - 1000) * 512 + t;
    if (n >= N) return;
    float cf = fmaxf(cnt_f[n], 1.0f), cr = fmaxf(cnt_r[n], 1.0f);
    posw[10*n+4] = a2f[2*n+0] / cf;
    posw[10*n+5] = a2f[2*n+1] / cf;
    posw[10*n+8] = a2r[2*n+0] / cr;
    posw[10*n+9] = a2r[2*n+1] / cr;
    return;
  }
  if ((int)blockIdx.x >= nNodeBlk) {           // S rows
    __shared__ float rs[2][256];
    int half = t >> 8, tc = t & 255;
    int r = (blockIdx.x - nNodeBlk) * 2 + half;
    rs[half][tc] = rel[(size_t)r*256 + tc];
    __syncthreads();
    float a = 0.f;
    for (int k = 0; k < 256; ++k) a = fmaf(rs[half][k], Wstr[(size_t)k*256 + tc], a);
    S[(size_t)r*256 + tc] = gateq[2] * (a + b_str[tc]);
    return;
  }
  __shared__ __align__(16) u16 AF[4*64*8];
  __shared__ __align__(16) u16 TT[64*512];
  const int wv = t >> 6, l = t & 63;
  const int lr = l & 15, lg = l >> 4;
  const int nb0 = blockIdx.x * 64;
  const float g0 = gateq[0];

  const int mt = t >> 7, half = (t >> 6) & 1, l2 = t & 63;
  int snode = nb0 + mt*16 + (l2 & 15);
  const float* srow = (snode < NT) ? (ent + (size_t)snode * EMB) : ntx;
  const int off = (l2 >> 4)*8 + half*4;

  f32x4 acc[4][4];
  #pragma unroll
  for (int m = 0; m < 4; ++m)
    #pragma unroll
    for (int n = 0; n < 4; ++n) acc[m][n] = (f32x4){0.f,0.f,0.f,0.f};

  float4 nxt = *(const float4*)(srow + off);
  for (int kc = 0; kc < 8; ++kc) {
    float4 cur = nxt;
    if (kc < 7) nxt = *(const float4*)(srow + (kc+1)*32 + off);
    {
      unsigned d0 = pk2(cur.x, cur.y), d1 = pk2(cur.z, cur.w);
      *(uint2*)&AF[((mt*64 + l2)*8 + half*4)] = make_uint2(d0, d1);
    }
    __syncthreads();
    short8v bn[4], af[4];
    #pragma unroll
    for (int n = 0; n < 4; ++n)
      bn[n] = *(const short8v*)&WN[((size_t)(kc*32 + wv*4 + n)*64 + l)*8];
    #pragma unroll
    for (int m = 0; m < 4; ++m)
      af[m] = *(const short8v*)&AF[(m*64 + l)*8];
    #pragma unroll
    for (int m = 0; m < 4; ++m)
      #pragma unroll
      for (int n = 0; n < 4; ++n)
        acc[m][n] = __builtin_amdgcn_mfma_f32_16x16x32_bf16(af[m], bn[n], acc[m][n], 0, 0, 0);
    __syncthreads();
  }
  #pragma unroll
  for (int m = 0; m < 4; ++m)
    #pragma unroll
    for (int n = 0; n < 4; ++n) {
      int col = wv*64 + n*16 + lr;
      float bias = (col < 256) ? b_nb[col] : 0.f;
      #pragma unroll
      for (int r2 = 0; r2 < 4; ++r2)
        TT[(m*16 + lg*4 + r2)*512 + col] = f2bf(g0 * (acc[m][n][r2] + bias));
    }
  __syncthreads();
  #pragma unroll
  for (int p = 0; p < 8; ++p) {
    int idx = p*512 + t;
    int nrow = idx >> 6, col = (idx & 63)*8;
    int node = nb0 + nrow;
    if (node <= NT) {
      uint4 v = *(const uint4*)&TT[nrow*512 + col];
      u16* dst = (col < 256) ? (TA + (size_t)node*256 + col)
                             : (TB + (size_t)node*256 + (col-256));
      *(uint4*)dst = v;
    }
  }
}

// ---------------- main kernel: 64 edges/block, 4 waves, 3 barriers ----------------
__global__ __launch_bounds__(256, 4)
void k_main(
    const int* __restrict__ h_id, const int* __restrict__ r_id, const int* __restrict__ t_id,
    const int* __restrict__ mids, const float* __restrict__ mwts,
    const float* __restrict__ W2, const float* __restrict__ b2,
    const float* __restrict__ pos, const float* __restrict__ gateq,
    const u16* __restrict__ WB, const float* __restrict__ S,
    const u16* __restrict__ TA, const u16* __restrict__ TB,
    float* __restrict__ out, int E, int NT)
{
  __shared__ __align__(16) u16 SH[20480];   // 40960 B total
  u16* FT2 = SH;                             // 32 KB: [kc][nt][64][8]
  u16* XB  = SH + 16384;                     // 4 KB: pos B-chunk
  u16* XB2 = SH + 18432;                     // 4 KB: motif-vec B-chunk
  float* woacc = (float*)(SH + 16384);       // aliases XB (dead by then)

  const int t  = threadIdx.x;
  const int wv = t >> 6, l = t & 63;
  const int Mw = wv >> 1, Nw = wv & 1;
  const int lr = l & 15, lg = l >> 4;
  const int be = blockIdx.x * 64;

  int eo = be + wv*16 + lr; if (eo >= E) eo = E - 1;
  const int hid = h_id[eo], tid = t_id[eo];

  // ===== A1: TA gathers async -> FT2 =====
  {
    const int hc = (hid < NT) ? hid : NT;
    const u16* paw = TA + (size_t)hc*256 + lg*8;
    #pragma unroll
    for (int kc = 0; kc < 8; ++kc)
      __builtin_amdgcn_global_load_lds(
        (const __attribute__((address_space(1))) unsigned int*)(paw + kc*32),
        (__attribute__((address_space(3))) unsigned int*)&FT2[kc*2048 + wv*512],
        16, 0, 0);
  }

  // ===== A2: pos -> XB (k==20 -> 1.0 bias row) =====
  {
    float vals[8];
    #pragma unroll
    for (int jp = 0; jp < 4; ++jp) {
      int k2 = lg*8 + jp*2;
      float2 f2;
      if (k2 < 10)       f2 = *(const float2*)&pos[(size_t)hid*10 + k2];
      else if (k2 < 20)  f2 = *(const float2*)&pos[(size_t)tid*10 + (k2 - 10)];
      else if (k2 == 20) f2 = make_float2(1.f, 0.f);
      else               f2 = make_float2(0.f, 0.f);
      vals[jp*2] = f2.x; vals[jp*2+1] = f2.y;
    }
    uint4 v = { pk2(vals[0],vals[1]), pk2(vals[2],vals[3]),
                pk2(vals[4],vals[5]), pk2(vals[6],vals[7]) };
    *(uint4*)&XB[(wv*64 + l)*8] = v;
  }

  // ===== A3: motif weight-vector -> XB2 =====
  {
    int4   mi0 = *(const int4*)  (mids + (size_t)eo*8);
    int4   mi1 = *(const int4*)  (mids + (size_t)eo*8 + 4);
    float4 mw0 = *(const float4*)(mwts + (size_t)eo*8);
    float4 mw1 = *(const float4*)(mwts + (size_t)eo*8 + 4);
    int   idv[8] = {mi0.x,mi0.y,mi0.z,mi0.w,mi1.x,mi1.y,mi1.z,mi1.w};
    float wtv[8] = {mw0.x,mw0.y,mw0.z,mw0.w,mw1.x,mw1.y,mw1.z,mw1.w};
    float s[8] = {0,0,0,0,0,0,0,0};
    #pragma unroll
    for (int j = 0; j < 8; ++j)
      #pragma unroll
      for (int i = 0; i < 8; ++i)
        s[i] += (idv[j] == lg*8 + i) ? wtv[j] : 0.f;
    uint4 v = { pk2(s[0],s[1]), pk2(s[2],s[3]), pk2(s[4],s[5]), pk2(s[6],s[7]) };
    *(uint4*)&XB2[(wv*64 + l)*8] = v;
  }

  // ===== A4: nb channel: TB via regs, TA from LDS; FT2 = relu(ta+tb) =====
  {
    const int tc2 = (tid < NT) ? tid : NT;
    const uint4* pb4 = (const uint4*)(TB + (size_t)tc2*256 + lg*8);
    uint4 tb0 = pb4[0];
    uint4 tb1 = pb4[4];
    asm volatile("s_waitcnt vmcnt(0)" ::: "memory");
    __builtin_amdgcn_sched_barrier(0);
    auto fuse = [](unsigned od, unsigned nd)->unsigned {
      float ol, oh, nl, nh;
      unpk(od, ol, oh); unpk(nd, nl, nh);
      return pk2(fmaxf(ol + nl, 0.f), fmaxf(oh + nh, 0.f));
    };
    #pragma unroll
    for (int kk = 0; kk < 8; kk += 2) {
      uint4 nba = tb0, nbb = tb1;
      if (kk < 6) { tb0 = pb4[(kk+2)*4]; tb1 = pb4[(kk+3)*4]; }
      #pragma unroll
      for (int c2 = 0; c2 < 2; ++c2) {
        uint4 nb = c2 ? nbb : nba;
        uint4* slot = (uint4*)&FT2[((kk+c2)*4 + wv)*512 + l*8];
        uint4 o = *slot;
        uint4 w;
        w.x = fuse(o.x, nb.x); w.y = fuse(o.y, nb.y);
        w.z = fuse(o.z, nb.z); w.w = fuse(o.w, nb.w);
        *slot = w;
      }
    }
  }

  f32x4 acc[8][2];
  auto zacc = [&]() {
    #pragma unroll
    for (int m = 0; m < 8; ++m)
      #pragma unroll
      for (int n = 0; n < 2; ++n) acc[m][n] = (f32x4){0.f,0.f,0.f,0.f};
  };
  auto mfma_chunk = [&](const u16* wc, const u16* xb) {
    short8v bfr[2];
    #pragma unroll
    for (int n = 0; n < 2; ++n)
      bfr[n] = *(const short8v*)&xb[((Nw*2 + n)*64 + l)*8];
    #pragma unroll
    for (int mh = 0; mh < 8; mh += 4) {
      short8v af[4];
      #pragma unroll
      for (int mm = 0; mm < 4; ++mm)
        af[mm] = *(const short8v*)&wc[((Mw*8 + mh + mm)*64 + l)*8];
      #pragma unroll
      for (int mm = 0; mm < 4; ++mm)
        #pragma unroll
        for (int n = 0; n < 2; ++n)
          acc[mh+mm][n] = __builtin_amdgcn_mfma_f32_16x16x32_bf16(af[mm], bfr[n], acc[mh+mm][n], 0, 0, 0);
    }
  };

  zacc();
  __syncthreads();                 // barrier 1: FT2 nb + XB + XB2 visible

  // ===== B1: pos MFMA + RMW combine (packed) =====
  mfma_chunk(WB, XB);
  {
    #pragma unroll
    for (int m = 0; m < 8; ++m) {
      int kc  = Mw*4 + ((m*4 + lg) >> 3);
      int lg2 = (m*2 + (lg >> 1)) & 3;
      #pragma unroll
      for (int n = 0; n < 2; ++n) {
        int nt = Nw*2 + n;
        int idx = ((kc*4 + nt)*64 + lg2*16 + lr)*8 + (lg & 1)*4;
        uint2* sp2 = (uint2*)&FT2[idx];
        uint2 o = *sp2;
        float ol, oh, pl, ph;
        unpk(o.x, ol, oh); unpk(o.y, pl, ph);
        o.x = pk2(ol + fmaxf(acc[m][n][0], 0.f), oh + fmaxf(acc[m][n][1], 0.f));
        o.y = pk2(pl + fmaxf(acc[m][n][2], 0.f), ph + fmaxf(acc[m][n][3], 0.f));
        *sp2 = o;
      }
    }
  }
  zacc();

  // ===== B2: motif MFMA + struct combine (packed) =====
  mfma_chunk(WB + 8192, XB2);
  {
    int r0 = be + (Nw*2 + 0)*16 + lr; if (r0 >= E) r0 = E - 1;
    int r1 = be + (Nw*2 + 1)*16 + lr; if (r1 >= E) r1 = E - 1;
    int rr[2] = { r_id[r0], r_id[r1] };
    #pragma unroll
    for (int m = 0; m < 8; ++m) {
      int f0 = Mw*128 + m*16 + lg*4;
      int kc  = Mw*4 + ((m*4 + lg) >> 3);
      int lg2 = (m*2 + (lg >> 1)) & 3;
      #pragma unroll
      for (int n = 0; n < 2; ++n) {
        int nt = Nw*2 + n;
        float4 sv = *(const float4*)&S[(size_t)rr[n]*256 + f0];
        int idx = ((kc*4 + nt)*64 + lg2*16 + lr)*8 + (lg & 1)*4;
        uint2* sp2 = (uint2*)&FT2[idx];
        uint2 o = *sp2;
        float ol, oh, pl, ph;
        unpk(o.x, ol, oh); unpk(o.y, pl, ph);
        o.x = pk2(ol + fmaxf(acc[m][n][0] + sv.x, 0.f),
                  oh + fmaxf(acc[m][n][1] + sv.y, 0.f));
        o.y = pk2(pl + fmaxf(acc[m][n][2] + sv.z, 0.f),
                  ph + fmaxf(acc[m][n][3] + sv.w, 0.f));
        *sp2 = o;
      }
    }
  }

  // ===== C: layer 1 (acc init = qpart), A = WB chunks 2..9, B = FT2 =====
  #pragma unroll
  for (int m = 0; m < 8; ++m) {
    int f0 = Mw*128 + m*16 + lg*4;
    float4 q4 = *(const float4*)&gateq[4 + f0];
    f32x4 qv = { q4.x, q4.y, q4.z, q4.w };
    acc[m][0] = qv; acc[m][1] = qv;
  }
  __syncthreads();                 // barrier 2: FT2 final for cross-wave reads
  for (int c2 = 0; c2 < 8; ++c2) {
    const u16* wc = WB + (size_t)(2 + c2) * 8192;
    short8v bfr[2];
    #pragma unroll
    for (int n = 0; n < 2; ++n)
      bfr[n] = *(const short8v*)&FT2[((c2*4 + Nw*2 + n)*64 + l)*8];
    #pragma unroll
    for (int mh = 0; mh < 8; mh += 4) {
      short8v af[4];
      #pragma unroll
      for (int mm = 0; mm < 4; ++mm)
        af[mm] = *(const short8v*)&wc[((Mw*8 + mh + mm)*64 + l)*8];
      #pragma unroll
      for (int mm = 0; mm < 4; ++mm)
        #pragma unroll
        for (int n = 0; n < 2; ++n)
          acc[mh+mm][n] = __builtin_amdgcn_mfma_f32_16x16x32_bf16(af[mm], bfr[n], acc[mh+mm][n], 0, 0, 0);
    }
  }

  // ===== layer 2 =====
  {
    #pragma unroll
    for (int n = 0; n < 2; ++n) {
      float p = 0.f;
      #pragma unroll
      for (int m = 0; m < 8; ++m) {
        int f0 = Mw*128 + m*16 + lg*4;
        float4 w4 = *(const float4*)&W2[f0];
        p = fmaf(fmaxf(acc[m][n][0], 0.f), w4.x, p);
        p = fmaf(fmaxf(acc[m][n][1], 0.f), w4.y, p);
        p = fmaf(fmaxf(acc[m][n][2], 0.f), w4.z, p);
        p = fmaf(fmaxf(acc[m][n][3], 0.f), w4.w, p);
      }
      p += __shfl_xor(p, 16);
      p += __shfl_xor(p, 32);
      if (lg == 0) woacc[Mw*64 + Nw*32 + n*16 + lr] = p;
    }
  }
  __syncthreads();                 // barrier 3
  if (t < 64) {
    int e = be + t;
    if (e < E)
      out[e] = woacc[t] + woacc[64 + t] + b2[0];
  }
}

extern "C" void kernel_launch(void* const* d_in, const int* in_sizes, int n_in,
                              void* d_out, int out_size, void* d_ws, size_t ws_size,
                              hipStream_t stream) {
  const int*   h_id  = (const int*)  d_in[0];
  const int*   r_id  = (const int*)  d_in[1];
  const int*   t_id  = (const int*)  d_in[2];
  const float* q     = (const float*)d_in[3];
  const float* ent   = (const float*)d_in[4];
  const float* rel   = (const float*)d_in[6];
  const float* topic = (const float*)d_in[7];
  const int*   mids  = (const int*)  d_in[8];
  const float* mwts  = (const float*)d_in[9];
  const float* ntx   = (const float*)d_in[10];
  const float* motif = (const float*)d_in[11];
  const float* W_nb  = (const float*)d_in[12];
  const float* b_nb  = (const float*)d_in[13];
  const float* W_pos = (const float*)d_in[14];
  const float* b_pos = (const float*)d_in[15];
  const float* W_str = (const float*)d_in[16];
  const float* b_str = (const float*)d_in[17];
  const float* W_g   = (const float*)d_in[18];
  const float* b_g   = (const float*)d_in[19];
  const float* W1    = (const float*)d_in[20];
  const float* b1    = (const float*)d_in[21];
  const float* W2    = (const float*)d_in[22];
  const float* b2    = (const float*)d_in[23];
  float* out = (float*)d_out;

  const int E  = in_sizes[0];
  const int NT = in_sizes[4] / EMB;   // 80000 text entities
  const int N  = in_sizes[7] / 2;     // 100000 total nodes

  float* ws    = (float*)d_ws;
  float* cnt_f = ws;
  float* cnt_r = ws + (size_t)N;
  float* a1f   = ws + (size_t)2*N;
  float* a1r   = ws + (size_t)4*N;
  float* a2f   = ws + (size_t)6*N;
  float* a2r   = ws + (size_t)8*N;
  float* pos   = ws + (size_t)10*N;             // N x 10
  float* gateq = ws + (size_t)20*N;             // [g0,g1,g2,pad, qpart(256)]
  u16*   WB    = (u16*)(ws + (size_t)20*N + 512);   // 10*8192 u16
  u16*   WN    = WB + (size_t)10*8192;              // 131072 u16
  float* S     = (float*)(WN + 131072);             // 2000*256 f32
  u16*   TA    = (u16*)(S + (size_t)2000*256);      // (NT+1) x 256 bf16
  u16*   TB    = TA + (size_t)(NT+1)*256;

  hipMemsetAsync(d_ws, 0, (size_t)10 * N * sizeof(float), stream);

  int gE = (E + 255) / 256, gN = (N + 255) / 256;
  int nNodeBlk = (NT + 64) / 64;
  int gD = (N + 511) / 512;
  k_scatter1 <<<gE, 256, 0, stream>>>(h_id, t_id, topic, cnt_f, cnt_r, a1f, a1r, E);
  k_div1_gate<<<gN + 1, 256, 0, stream>>>(topic, cnt_f, cnt_r, a1f, a1r, pos, N,
                                          q, W_g, b_g, W1, b1, gateq);
  k_scatter2 <<<gE, 256, 0, stream>>>(h_id, t_id, pos, a2f, a2r, E);
  k_wtrans   <<<104, 256, 0, stream>>>(W_pos, W_str, W1, W_nb, b_pos, motif, gateq,
                                       WB, WN);
  k_node_S   <<<nNodeBlk + 1000 + gD, 512, 0, stream>>>(ent, ntx, WN, TA, TB, NT, nNodeBlk,
                                                        rel, W_str, b_nb, b_str, gateq,
                                                        cnt_f, cnt_r, a2f, a2r, pos, N, S);

  int gM = (E + 63) / 64;
  k_main<<<gM, 256, 0, stream>>>(h_id, r_id, t_id, mids, mwts,
                                 W2, b2, pos, gateq, WB, S, TA, TB, out, E, NT);
}

// Round 15
// 270.231 us; speedup vs baseline: 3.8674x; 1.1885x over previous
//
#include <hip/hip_runtime.h>

#define EMB 256
typedef unsigned short u16;
typedef __attribute__((ext_vector_type(8))) short short8v;
typedef __attribute__((ext_vector_type(4))) short short4v;
typedef __attribute__((ext_vector_type(4))) float f32x4;

__device__ inline u16 f2bf(float x){
  union{float f; unsigned u;} c; c.f = x;
  unsigned r = c.u + 0x7FFFu + ((c.u>>16)&1u);
  return (u16)(r>>16);
}
__device__ inline float bf2f(u16 h){
  union{unsigned u; float f;} c; c.u = ((unsigned)h) << 16; return c.f;
}
// packed bf16 pack/unpack (RNE, matches f2bf)
__device__ inline unsigned pk2(float a, float b){
  unsigned r;
  asm("v_cvt_pk_bf16_f32 %0, %1, %2" : "=v"(r) : "v"(a), "v"(b));
  return r;
}
__device__ inline void unpk(unsigned d, float& lo, float& hi){
  union{unsigned u; float f;} a, b;
  a.u = d << 16; b.u = d & 0xffff0000u;
  lo = a.f; hi = b.f;
}

// ---------------- DDE round 1: counts + SPARSE topic0 scatter ----------------
// topic[:,1] == 1 - topic[:,0] exactly, so only col-0 (sparse ~0.1%) needs atomics.
__global__ void k_scatter1(const int* __restrict__ h_id, const int* __restrict__ t_id,
                           const float* __restrict__ topic,
                           float* __restrict__ cnt_f, float* __restrict__ cnt_r,
                           float* __restrict__ accf0, float* __restrict__ accr0, int E) {
  int e = blockIdx.x * 256 + threadIdx.x;
  if (e >= E) return;
  int h = h_id[e], t = t_id[e];
  atomicAdd(&cnt_f[t], 1.0f);
  atomicAdd(&cnt_r[h], 1.0f);
  float a0 = topic[2*h];
  if (a0 != 0.f) atomicAdd(&accf0[t], a0);
  float c0 = topic[2*t];
  if (c0 != 0.f) atomicAdd(&accr0[h], c0);
}

// block 0: gate softmax + qpart; blocks 1..gN: div1 (col1 via identity cnt-acc0)
__global__ void k_div1_gate(const float* __restrict__ topic,
                            const float* __restrict__ cnt_f, const float* __restrict__ cnt_r,
                            const float* __restrict__ accf0, const float* __restrict__ accr0,
                            float* __restrict__ pos, int N,
                            const float* __restrict__ q, const float* __restrict__ Wg,
                            const float* __restrict__ bg, const float* __restrict__ W1,
                            const float* __restrict__ b1, float* __restrict__ gateq) {
  int t = threadIdx.x;
  if (blockIdx.x == 0) {
    __shared__ float qs[256];
    __shared__ float z[3];
    qs[t] = q[t];
    __syncthreads();
    if (t < 3) {
      float s = bg[t];
      for (int k = 0; k < 256; ++k) s += qs[k] * Wg[k*3 + t];
      z[t] = s;
    }
    __syncthreads();
    if (t == 0) {
      float m = fmaxf(z[0], fmaxf(z[1], z[2]));
      float e0 = expf(z[0]-m), e1 = expf(z[1]-m), e2 = expf(z[2]-m);
      float s = e0 + e1 + e2;
      gateq[0] = e0/s; gateq[1] = e1/s; gateq[2] = e2/s; gateq[3] = 0.f;
    }
    float a = b1[t];
    for (int k = 0; k < 256; ++k) a += qs[k] * W1[k*256 + t];
    gateq[4 + t] = a;
    return;
  }
  int n = (blockIdx.x - 1) * 256 + t;
  if (n >= N) return;
  float cntf = cnt_f[n], cntr = cnt_r[n];
  float cf = fmaxf(cntf, 1.0f), cr = fmaxf(cntr, 1.0f);
  float t0 = topic[2*n];
  float af = accf0[n], ar = accr0[n];
  pos[10*n+0] = t0;
  pos[10*n+1] = 1.0f - t0;
  pos[10*n+2] = af / cf;
  pos[10*n+3] = (cntf - af) / cf;
  pos[10*n+6] = ar / cr;
  pos[10*n+7] = (cntr - ar) / cr;
}

// ---------------- DDE round 2: SPARSE scatter via z-identity ----------------
// pos3[h] = 1 - pos2[h] - z[h], z[h]=[cnt_f[h]==0]  =>  accumulate only pos2 (sparse)
// and z (sparse); dense part recovered as cnt_f[t] - a2f0 - zf in div2.
__global__ void k_scatter2(const int* __restrict__ h_id, const int* __restrict__ t_id,
                           const float* __restrict__ pos,
                           const float* __restrict__ cnt_f, const float* __restrict__ cnt_r,
                           float* __restrict__ a2f0, float* __restrict__ zf,
                           float* __restrict__ a2r0, float* __restrict__ zr, int E) {
  int e = blockIdx.x * 256 + threadIdx.x;
  if (e >= E) return;
  int h = h_id[e], t = t_id[e];
  float p2 = pos[10*h+2];
  if (p2 != 0.f) atomicAdd(&a2f0[t], p2);
  if (cnt_f[h] == 0.f) atomicAdd(&zf[t], 1.0f);
  float p6 = pos[10*t+6];
  if (p6 != 0.f) atomicAdd(&a2r0[h], p6);
  if (cnt_r[t] == 0.f) atomicAdd(&zr[h], 1.0f);
}

// ---------------- weight transforms (gate-folded) ----------------
__global__ void k_wtrans(const float* __restrict__ Wpos, const float* __restrict__ Wstr,
                         const float* __restrict__ W1, const float* __restrict__ Wnb,
                         const float* __restrict__ bpos, const float* __restrict__ motif,
                         const float* __restrict__ gateq,
                         u16* __restrict__ WB, u16* __restrict__ WN) {
  int gid = blockIdx.x * 256 + threadIdx.x;
  if (gid < 10*1024) {
    int lane = gid & 63, ft = (gid >> 6) & 15, kt = gid >> 10;
    int n  = ft*16 + (lane & 15);
    int k0 = (lane >> 4) * 8;
    short8v v;
    if (kt == 0) {
      float g1 = gateq[1];
      #pragma unroll
      for (int j = 0; j < 8; ++j) {
        int k = k0 + j;
        float x = (k < 20) ? g1 * Wpos[(size_t)k*256 + n]
                : (k == 20) ? g1 * bpos[n] : 0.f;
        v[j] = (short)f2bf(x);
      }
    } else if (kt == 1) {
      float g2 = gateq[2];
      #pragma unroll
      for (int j = 0; j < 8; ++j) {
        int m = k0 + j;
        float x = 0.f;
        if (m >= 1 && m < 17) {
          float a = 0.f;
          for (int k = 0; k < 64; ++k)
            a = fmaf(motif[(size_t)m*64 + k], Wstr[(size_t)(256+k)*256 + n], a);
          x = g2 * a;
        }
        v[j] = (short)f2bf(x);
      }
    } else {
      int kb = (kt - 2) * 32;
      #pragma unroll
      for (int j = 0; j < 8; ++j)
        v[j] = (short)f2bf(W1[(size_t)(256 + kb + k0 + j)*256 + n]);
    }
    *(short8v*)(WB + (size_t)gid * 8) = v;
  } else {
    int g = gid - 10240;
    if (g >= 8*32*64) return;
    int lane = g & 63, nt = (g >> 6) & 31, kc = g >> 11;
    int col = nt*16 + (lane & 15);
    int k0  = kc*32 + (lane >> 4) * 8;
    short8v v;
    #pragma unroll
    for (int j = 0; j < 8; ++j) {
      int k = k0 + j;
      float x = (col < 256) ? Wnb[(size_t)k*256 + col] : Wnb[(size_t)(256+k)*256 + (col-256)];
      v[j] = (short)f2bf(x);
    }
    *(short8v*)(WN + (size_t)g * 8) = v;
  }
}

// ---------------- node tables + S + div2 tail ----------------
__global__ __launch_bounds__(512) void k_node_S(const float* __restrict__ ent,
                                                const float* __restrict__ ntx,
                                                const u16* __restrict__ WN,
                                                u16* __restrict__ TA, u16* __restrict__ TB,
                                                int NT, int nNodeBlk,
                                                const float* __restrict__ rel,
                                                const float* __restrict__ Wstr,
                                                const float* __restrict__ b_nb,
                                                const float* __restrict__ b_str,
                                                const float* __restrict__ gateq,
                                                const float* __restrict__ cnt_f,
                                                const float* __restrict__ cnt_r,
                                                const float* __restrict__ a2f0,
                                                const float* __restrict__ zf,
                                                const float* __restrict__ a2r0,
                                                const float* __restrict__ zr,
                                                float* __restrict__ posw, int N,
                                                float* __restrict__ S) {
  const int t = threadIdx.x;
  if ((int)blockIdx.x >= nNodeBlk + 1000) {    // div2 tail (z-identity)
    int n = ((int)blockIdx.x - nNodeBlk - 1000) * 512 + t;
    if (n >= N) return;
    float cntf = cnt_f[n], cntr = cnt_r[n];
    float cf = fmaxf(cntf, 1.0f), cr = fmaxf(cntr, 1.0f);
    float af = a2f0[n], ar = a2r0[n];
    posw[10*n+4] = af / cf;
    posw[10*n+5] = (cntf - af - zf[n]) / cf;
    posw[10*n+8] = ar / cr;
    posw[10*n+9] = (cntr - ar - zr[n]) / cr;
    return;
  }
  if ((int)blockIdx.x >= nNodeBlk) {           // S rows
    __shared__ float rs[2][256];
    int half = t >> 8, tc = t & 255;
    int r = (blockIdx.x - nNodeBlk) * 2 + half;
    rs[half][tc] = rel[(size_t)r*256 + tc];
    __syncthreads();
    float a = 0.f;
    for (int k = 0; k < 256; ++k) a = fmaf(rs[half][k], Wstr[(size_t)k*256 + tc], a);
    S[(size_t)r*256 + tc] = gateq[2] * (a + b_str[tc]);
    return;
  }
  __shared__ __align__(16) u16 AF[4*64*8];
  __shared__ __align__(16) u16 TT[64*512];
  const int wv = t >> 6, l = t & 63;
  const int lr = l & 15, lg = l >> 4;
  const int nb0 = blockIdx.x * 64;
  const float g0 = gateq[0];

  const int mt = t >> 7, half = (t >> 6) & 1, l2 = t & 63;
  int snode = nb0 + mt*16 + (l2 & 15);
  const float* srow = (snode < NT) ? (ent + (size_t)snode * EMB) : ntx;
  const int off = (l2 >> 4)*8 + half*4;

  f32x4 acc[4][4];
  #pragma unroll
  for (int m = 0; m < 4; ++m)
    #pragma unroll
    for (int n = 0; n < 4; ++n) acc[m][n] = (f32x4){0.f,0.f,0.f,0.f};

  float4 nxt = *(const float4*)(srow + off);
  for (int kc = 0; kc < 8; ++kc) {
    float4 cur = nxt;
    if (kc < 7) nxt = *(const float4*)(srow + (kc+1)*32 + off);
    {
      unsigned d0 = pk2(cur.x, cur.y), d1 = pk2(cur.z, cur.w);
      *(uint2*)&AF[((mt*64 + l2)*8 + half*4)] = make_uint2(d0, d1);
    }
    __syncthreads();
    short8v bn[4], af[4];
    #pragma unroll
    for (int n = 0; n < 4; ++n)
      bn[n] = *(const short8v*)&WN[((size_t)(kc*32 + wv*4 + n)*64 + l)*8];
    #pragma unroll
    for (int m = 0; m < 4; ++m)
      af[m] = *(const short8v*)&AF[(m*64 + l)*8];
    #pragma unroll
    for (int m = 0; m < 4; ++m)
      #pragma unroll
      for (int n = 0; n < 4; ++n)
        acc[m][n] = __builtin_amdgcn_mfma_f32_16x16x32_bf16(af[m], bn[n], acc[m][n], 0, 0, 0);
    __syncthreads();
  }
  #pragma unroll
  for (int m = 0; m < 4; ++m)
    #pragma unroll
    for (int n = 0; n < 4; ++n) {
      int col = wv*64 + n*16 + lr;
      float bias = (col < 256) ? b_nb[col] : 0.f;
      #pragma unroll
      for (int r2 = 0; r2 < 4; ++r2)
        TT[(m*16 + lg*4 + r2)*512 + col] = f2bf(g0 * (acc[m][n][r2] + bias));
    }
  __syncthreads();
  #pragma unroll
  for (int p = 0; p < 8; ++p) {
    int idx = p*512 + t;
    int nrow = idx >> 6, col = (idx & 63)*8;
    int node = nb0 + nrow;
    if (node <= NT) {
      uint4 v = *(const uint4*)&TT[nrow*512 + col];
      u16* dst = (col < 256) ? (TA + (size_t)node*256 + col)
                             : (TB + (size_t)node*256 + (col-256));
      *(uint4*)dst = v;
    }
  }
}

// ---------------- main kernel: 64 edges/block, 4 waves, 3 barriers ----------------
__global__ __launch_bounds__(256, 4)
void k_main(
    const int* __restrict__ h_id, const int* __restrict__ r_id, const int* __restrict__ t_id,
    const int* __restrict__ mids, const float* __restrict__ mwts,
    const float* __restrict__ W2, const float* __restrict__ b2,
    const float* __restrict__ pos, const float* __restrict__ gateq,
    const u16* __restrict__ WB, const float* __restrict__ S,
    const u16* __restrict__ TA, const u16* __restrict__ TB,
    float* __restrict__ out, int E, int NT)
{
  __shared__ __align__(16) u16 SH[20480];   // 40960 B total
  u16* FT2 = SH;                             // 32 KB: [kc][nt][64][8]
  u16* XB  = SH + 16384;                     // 4 KB: pos B-chunk
  u16* XB2 = SH + 18432;                     // 4 KB: motif-vec B-chunk
  float* woacc = (float*)(SH + 16384);       // aliases XB (dead by then)

  const int t  = threadIdx.x;
  const int wv = t >> 6, l = t & 63;
  const int Mw = wv >> 1, Nw = wv & 1;
  const int lr = l & 15, lg = l >> 4;
  const int be = blockIdx.x * 64;

  int eo = be + wv*16 + lr; if (eo >= E) eo = E - 1;
  const int hid = h_id[eo], tid = t_id[eo];

  // prefetch r_ids for B2's S gathers (breaks the mid-kernel r_id->S chain)
  int r0 = be + (Nw*2 + 0)*16 + lr; if (r0 >= E) r0 = E - 1;
  int r1 = be + (Nw*2 + 1)*16 + lr; if (r1 >= E) r1 = E - 1;
  const int rr0 = r_id[r0], rr1 = r_id[r1];

  // ===== A1: TA gathers async -> FT2 =====
  {
    const int hc = (hid < NT) ? hid : NT;
    const u16* paw = TA + (size_t)hc*256 + lg*8;
    #pragma unroll
    for (int kc = 0; kc < 8; ++kc)
      __builtin_amdgcn_global_load_lds(
        (const __attribute__((address_space(1))) unsigned int*)(paw + kc*32),
        (__attribute__((address_space(3))) unsigned int*)&FT2[kc*2048 + wv*512],
        16, 0, 0);
  }

  // ===== A2: pos -> XB (k==20 -> 1.0 bias row) =====
  {
    float vals[8];
    #pragma unroll
    for (int jp = 0; jp < 4; ++jp) {
      int k2 = lg*8 + jp*2;
      float2 f2;
      if (k2 < 10)       f2 = *(const float2*)&pos[(size_t)hid*10 + k2];
      else if (k2 < 20)  f2 = *(const float2*)&pos[(size_t)tid*10 + (k2 - 10)];
      else if (k2 == 20) f2 = make_float2(1.f, 0.f);
      else               f2 = make_float2(0.f, 0.f);
      vals[jp*2] = f2.x; vals[jp*2+1] = f2.y;
    }
    uint4 v = { pk2(vals[0],vals[1]), pk2(vals[2],vals[3]),
                pk2(vals[4],vals[5]), pk2(vals[6],vals[7]) };
    *(uint4*)&XB[(wv*64 + l)*8] = v;
  }

  // ===== A3: motif weight-vector -> XB2 =====
  {
    int4   mi0 = *(const int4*)  (mids + (size_t)eo*8);
    int4   mi1 = *(const int4*)  (mids + (size_t)eo*8 + 4);
    float4 mw0 = *(const float4*)(mwts + (size_t)eo*8);
    float4 mw1 = *(const float4*)(mwts + (size_t)eo*8 + 4);
    int   idv[8] = {mi0.x,mi0.y,mi0.z,mi0.w,mi1.x,mi1.y,mi1.z,mi1.w};
    float wtv[8] = {mw0.x,mw0.y,mw0.z,mw0.w,mw1.x,mw1.y,mw1.z,mw1.w};
    float s[8] = {0,0,0,0,0,0,0,0};
    #pragma unroll
    for (int j = 0; j < 8; ++j)
      #pragma unroll
      for (int i = 0; i < 8; ++i)
        s[i] += (idv[j] == lg*8 + i) ? wtv[j] : 0.f;
    uint4 v = { pk2(s[0],s[1]), pk2(s[2],s[3]), pk2(s[4],s[5]), pk2(s[6],s[7]) };
    *(uint4*)&XB2[(wv*64 + l)*8] = v;
  }

  // ===== A4: nb channel: TB via regs, TA from LDS; FT2 = relu(ta+tb) =====
  {
    const int tc2 = (tid < NT) ? tid : NT;
    const uint4* pb4 = (const uint4*)(TB + (size_t)tc2*256 + lg*8);
    uint4 tb0 = pb4[0];
    uint4 tb1 = pb4[4];
    asm volatile("s_waitcnt vmcnt(0)" ::: "memory");
    __builtin_amdgcn_sched_barrier(0);
    auto fuse = [](unsigned od, unsigned nd)->unsigned {
      float ol, oh, nl, nh;
      unpk(od, ol, oh); unpk(nd, nl, nh);
      return pk2(fmaxf(ol + nl, 0.f), fmaxf(oh + nh, 0.f));
    };
    #pragma unroll
    for (int kk = 0; kk < 8; kk += 2) {
      uint4 nba = tb0, nbb = tb1;
      if (kk < 6) { tb0 = pb4[(kk+2)*4]; tb1 = pb4[(kk+3)*4]; }
      #pragma unroll
      for (int c2 = 0; c2 < 2; ++c2) {
        uint4 nb = c2 ? nbb : nba;
        uint4* slot = (uint4*)&FT2[((kk+c2)*4 + wv)*512 + l*8];
        uint4 o = *slot;
        uint4 w;
        w.x = fuse(o.x, nb.x); w.y = fuse(o.y, nb.y);
        w.z = fuse(o.z, nb.z); w.w = fuse(o.w, nb.w);
        *slot = w;
      }
    }
  }

  f32x4 acc[8][2];
  auto zacc = [&]() {
    #pragma unroll
    for (int m = 0; m < 8; ++m)
      #pragma unroll
      for (int n = 0; n < 2; ++n) acc[m][n] = (f32x4){0.f,0.f,0.f,0.f};
  };
  auto mfma_chunk = [&](const u16* wc, const u16* xb) {
    short8v bfr[2];
    #pragma unroll
    for (int n = 0; n < 2; ++n)
      bfr[n] = *(const short8v*)&xb[((Nw*2 + n)*64 + l)*8];
    #pragma unroll
    for (int mh = 0; mh < 8; mh += 4) {
      short8v af[4];
      #pragma unroll
      for (int mm = 0; mm < 4; ++mm)
        af[mm] = *(const short8v*)&wc[((Mw*8 + mh + mm)*64 + l)*8];
      #pragma unroll
      for (int mm = 0; mm < 4; ++mm)
        #pragma unroll
        for (int n = 0; n < 2; ++n)
          acc[mh+mm][n] = __builtin_amdgcn_mfma_f32_16x16x32_bf16(af[mm], bfr[n], acc[mh+mm][n], 0, 0, 0);
    }
  };

  zacc();
  __syncthreads();                 // barrier 1: FT2 nb + XB + XB2 visible

  // ===== B1: pos MFMA + RMW combine (packed) =====
  mfma_chunk(WB, XB);
  {
    #pragma unroll
    for (int m = 0; m < 8; ++m) {
      int kc  = Mw*4 + ((m*4 + lg) >> 3);
      int lg2 = (m*2 + (lg >> 1)) & 3;
      #pragma unroll
      for (int n = 0; n < 2; ++n) {
        int nt = Nw*2 + n;
        int idx = ((kc*4 + nt)*64 + lg2*16 + lr)*8 + (lg & 1)*4;
        uint2* sp2 = (uint2*)&FT2[idx];
        uint2 o = *sp2;
        float ol, oh, pl, ph;
        unpk(o.x, ol, oh); unpk(o.y, pl, ph);
        o.x = pk2(ol + fmaxf(acc[m][n][0], 0.f), oh + fmaxf(acc[m][n][1], 0.f));
        o.y = pk2(pl + fmaxf(acc[m][n][2], 0.f), ph + fmaxf(acc[m][n][3], 0.f));
        *sp2 = o;
      }
    }
  }
  zacc();

  // ===== B2: motif MFMA + struct combine (packed) =====
  mfma_chunk(WB + 8192, XB2);
  {
    int rr[2] = { rr0, rr1 };
    #pragma unroll
    for (int m = 0; m < 8; ++m) {
      int f0 = Mw*128 + m*16 + lg*4;
      int kc  = Mw*4 + ((m*4 + lg) >> 3);
      int lg2 = (m*2 + (lg >> 1)) & 3;
      #pragma unroll
      for (int n = 0; n < 2; ++n) {
        int nt = Nw*2 + n;
        float4 sv = *(const float4*)&S[(size_t)rr[n]*256 + f0];
        int idx = ((kc*4 + nt)*64 + lg2*16 + lr)*8 + (lg & 1)*4;
        uint2* sp2 = (uint2*)&FT2[idx];
        uint2 o = *sp2;
        float ol, oh, pl, ph;
        unpk(o.x, ol, oh); unpk(o.y, pl, ph);
        o.x = pk2(ol + fmaxf(acc[m][n][0] + sv.x, 0.f),
                  oh + fmaxf(acc[m][n][1] + sv.y, 0.f));
        o.y = pk2(pl + fmaxf(acc[m][n][2] + sv.z, 0.f),
                  ph + fmaxf(acc[m][n][3] + sv.w, 0.f));
        *sp2 = o;
      }
    }
  }

  // ===== C: layer 1 (acc init = qpart), A = WB chunks 2..9, B = FT2 =====
  #pragma unroll
  for (int m = 0; m < 8; ++m) {
    int f0 = Mw*128 + m*16 + lg*4;
    float4 q4 = *(const float4*)&gateq[4 + f0];
    f32x4 qv = { q4.x, q4.y, q4.z, q4.w };
    acc[m][0] = qv; acc[m][1] = qv;
  }
  __syncthreads();                 // barrier 2: FT2 final for cross-wave reads
  for (int c2 = 0; c2 < 8; ++c2) {
    const u16* wc = WB + (size_t)(2 + c2) * 8192;
    short8v bfr[2];
    #pragma unroll
    for (int n = 0; n < 2; ++n)
      bfr[n] = *(const short8v*)&FT2[((c2*4 + Nw*2 + n)*64 + l)*8];
    #pragma unroll
    for (int mh = 0; mh < 8; mh += 4) {
      short8v af[4];
      #pragma unroll
      for (int mm = 0; mm < 4; ++mm)
        af[mm] = *(const short8v*)&wc[((Mw*8 + mh + mm)*64 + l)*8];
      #pragma unroll
      for (int mm = 0; mm < 4; ++mm)
        #pragma unroll
        for (int n = 0; n < 2; ++n)
          acc[mh+mm][n] = __builtin_amdgcn_mfma_f32_16x16x32_bf16(af[mm], bfr[n], acc[mh+mm][n], 0, 0, 0);
    }
  }

  // ===== layer 2 =====
  {
    #pragma unroll
    for (int n = 0; n < 2; ++n) {
      float p = 0.f;
      #pragma unroll
      for (int m = 0; m < 8; ++m) {
        int f0 = Mw*128 + m*16 + lg*4;
        float4 w4 = *(const float4*)&W2[f0];
        p = fmaf(fmaxf(acc[m][n][0], 0.f), w4.x, p);
        p = fmaf(fmaxf(acc[m][n][1], 0.f), w4.y, p);
        p = fmaf(fmaxf(acc[m][n][2], 0.f), w4.z, p);
        p = fmaf(fmaxf(acc[m][n][3], 0.f), w4.w, p);
      }
      p += __shfl_xor(p, 16);
      p += __shfl_xor(p, 32);
      if (lg == 0) woacc[Mw*64 + Nw*32 + n*16 + lr] = p;
    }
  }
  __syncthreads();                 // barrier 3
  if (t < 64) {
    int e = be + t;
    if (e < E)
      out[e] = woacc[t] + woacc[64 + t] + b2[0];
  }
}

extern "C" void kernel_launch(void* const* d_in, const int* in_sizes, int n_in,
                              void* d_out, int out_size, void* d_ws, size_t ws_size,
                              hipStream_t stream) {
  const int*   h_id  = (const int*)  d_in[0];
  const int*   r_id  = (const int*)  d_in[1];
  const int*   t_id  = (const int*)  d_in[2];
  const float* q     = (const float*)d_in[3];
  const float* ent   = (const float*)d_in[4];
  const float* rel   = (const float*)d_in[6];
  const float* topic = (const float*)d_in[7];
  const int*   mids  = (const int*)  d_in[8];
  const float* mwts  = (const float*)d_in[9];
  const float* ntx   = (const float*)d_in[10];
  const float* motif = (const float*)d_in[11];
  const float* W_nb  = (const float*)d_in[12];
  const float* b_nb  = (const float*)d_in[13];
  const float* W_pos = (const float*)d_in[14];
  const float* b_pos = (const float*)d_in[15];
  const float* W_str = (const float*)d_in[16];
  const float* b_str = (const float*)d_in[17];
  const float* W_g   = (const float*)d_in[18];
  const float* b_g   = (const float*)d_in[19];
  const float* W1    = (const float*)d_in[20];
  const float* b1    = (const float*)d_in[21];
  const float* W2    = (const float*)d_in[22];
  const float* b2    = (const float*)d_in[23];
  float* out = (float*)d_out;

  const int E  = in_sizes[0];
  const int NT = in_sizes[4] / EMB;   // 80000 text entities
  const int N  = in_sizes[7] / 2;     // 100000 total nodes

  float* ws    = (float*)d_ws;
  float* cnt_f = ws;
  float* cnt_r = ws + (size_t)N;
  float* a1f0  = ws + (size_t)2*N;
  float* a1r0  = ws + (size_t)3*N;
  float* a2f0  = ws + (size_t)4*N;
  float* zfb   = ws + (size_t)5*N;
  float* a2r0  = ws + (size_t)6*N;
  float* zrb   = ws + (size_t)7*N;
  float* pos   = ws + (size_t)10*N;             // N x 10
  float* gateq = ws + (size_t)20*N;             // [g0,g1,g2,pad, qpart(256)]
  u16*   WB    = (u16*)(ws + (size_t)20*N + 512);   // 10*8192 u16
  u16*   WN    = WB + (size_t)10*8192;              // 131072 u16
  float* S     = (float*)(WN + 131072);             // 2000*256 f32
  u16*   TA    = (u16*)(S + (size_t)2000*256);      // (NT+1) x 256 bf16
  u16*   TB    = TA + (size_t)(NT+1)*256;

  hipMemsetAsync(d_ws, 0, (size_t)10 * N * sizeof(float), stream);

  int gE = (E + 255) / 256, gN = (N + 255) / 256;
  int nNodeBlk = (NT + 64) / 64;
  int gD = (N + 511) / 512;
  k_scatter1 <<<gE, 256, 0, stream>>>(h_id, t_id, topic, cnt_f, cnt_r, a1f0, a1r0, E);
  k_div1_gate<<<gN + 1, 256, 0, stream>>>(topic, cnt_f, cnt_r, a1f0, a1r0, pos, N,
                                          q, W_g, b_g, W1, b1, gateq);
  k_scatter2 <<<gE, 256, 0, stream>>>(h_id, t_id, pos, cnt_f, cnt_r,
                                      a2f0, zfb, a2r0, zrb, E);
  k_wtrans   <<<104, 256, 0, stream>>>(W_pos, W_str, W1, W_nb, b_pos, motif, gateq,
                                       WB, WN);
  k_node_S   <<<nNodeBlk + 1000 + gD, 512, 0, stream>>>(ent, ntx, WN, TA, TB, NT, nNodeBlk,
                                                        rel, W_str, b_nb, b_str, gateq,
                                                        cnt_f, cnt_r, a2f0, zfb, a2r0, zrb,
                                                        pos, N, S);

  int gM = (E + 63) / 64;
  k_main<<<gM, 256, 0, stream>>>(h_id, r_id, t_id, mids, mwts,
                                 W2, b2, pos, gateq, WB, S, TA, TB, out, E, NT);
}